// Round 2
// baseline (4385.080 us; speedup 1.0000x reference)
//
#include <hip/hip_runtime.h>
#include <hip/hip_bf16.h>
#include <math.h>

#define NB 4
#define NS 2048
#define ND 768
#define NH 8
#define NDH 96
#define NHID 3072
#define NROWS (NB*NS)

// ---------------- block-wide sum over 256 threads ----------------
static __device__ __forceinline__ float block_sum256(float v) {
    __shared__ float red[4];
    #pragma unroll
    for (int o = 32; o > 0; o >>= 1) v += __shfl_down(v, o);
    int w = threadIdx.x >> 6;
    __syncthreads();                 // protect red from previous use
    if ((threadIdx.x & 63) == 0) red[w] = v;
    __syncthreads();
    return red[0] + red[1] + red[2] + red[3];
}

// ---------------- LayerNorm: one block per row of 768 ----------------
__global__ __launch_bounds__(256) void ln_kernel(const float* __restrict__ in,
                                                 const float* __restrict__ g,
                                                 const float* __restrict__ bta,
                                                 float* __restrict__ out) {
    int row = blockIdx.x;
    const float* x = in + (size_t)row * ND;
    int t = threadIdx.x;
    float v0 = x[t], v1 = x[t + 256], v2 = x[t + 512];
    float mu = block_sum256(v0 + v1 + v2) * (1.0f / ND);
    float d0 = v0 - mu, d1 = v1 - mu, d2 = v2 - mu;
    float var = block_sum256(d0*d0 + d1*d1 + d2*d2) * (1.0f / ND);
    float rs = rsqrtf(var + 1e-6f);
    float* o = out + (size_t)row * ND;
    o[t]       = d0 * rs * g[t]       + bta[t];
    o[t + 256] = d1 * rs * g[t + 256] + bta[t + 256];
    o[t + 512] = d2 * rs * g[t + 512] + bta[t + 512];
}

// ---------------- f32 tiled GEMM, 64x64x16, 256 threads, 4x4/thread ----------------
// EPI: 0 = QKV scatter (+bias), 1 = +bias +residual, 2 = +bias +exact GELU
template<int EPI>
__global__ __launch_bounds__(256) void gemm_kernel(
        const float* __restrict__ A, const float* __restrict__ Bw,
        const float* __restrict__ bias, float* __restrict__ Cout,
        const float* __restrict__ res,
        float* __restrict__ qo, float* __restrict__ ko, float* __restrict__ vo,
        int M, int N, int K) {
    __shared__ float As[16][68];   // transposed A tile [k][m], pad->16B-aligned float4 rows
    __shared__ float Bs[16][64];
    int nb = N >> 6;
    int bx = blockIdx.x % nb, by = blockIdx.x / nb;
    int t = threadIdx.x;
    int tx = t & 15, ty = t >> 4;
    int arow = t >> 2,  ac4 = (t & 3) << 2;
    int brow = t >> 4,  bc4 = (t & 15) << 2;
    const float* Ab = A + (size_t)(by * 64) * K;
    const float* Bb = Bw + bx * 64;
    float acc[4][4] = {};
    for (int k0 = 0; k0 < K; k0 += 16) {
        float4 a4 = *(const float4*)&Ab[(size_t)arow * K + k0 + ac4];
        float4 b4 = *(const float4*)&Bb[(size_t)(k0 + brow) * N + bc4];
        __syncthreads();
        As[ac4 + 0][arow] = a4.x; As[ac4 + 1][arow] = a4.y;
        As[ac4 + 2][arow] = a4.z; As[ac4 + 3][arow] = a4.w;
        *(float4*)&Bs[brow][bc4] = b4;
        __syncthreads();
        #pragma unroll
        for (int kk = 0; kk < 16; ++kk) {
            float4 av = *(const float4*)&As[kk][ty << 2];
            float4 bv = *(const float4*)&Bs[kk][tx << 2];
            float aa[4] = {av.x, av.y, av.z, av.w};
            float bb[4] = {bv.x, bv.y, bv.z, bv.w};
            #pragma unroll
            for (int i = 0; i < 4; ++i)
                #pragma unroll
                for (int j = 0; j < 4; ++j)
                    acc[i][j] += aa[i] * bb[j];
        }
    }
    int r0 = (by << 6) + (ty << 2), c0 = (bx << 6) + (tx << 2);
    #pragma unroll
    for (int i = 0; i < 4; ++i) {
        int r = r0 + i;
        #pragma unroll
        for (int j = 0; j < 4; ++j) {
            int c = c0 + j;
            float val = acc[i][j] + bias[c];
            if (EPI == 0) {
                int which = c / ND;
                int cc = c - which * ND;
                int hh = cc / NDH, dd = cc - hh * NDH;
                int b_ = r >> 11, s_ = r & (NS - 1);
                float* dst = (which == 0) ? qo : (which == 1) ? ko : vo;
                dst[(size_t)((b_ * NH + hh) * NS + s_) * NDH + dd] = val;
            } else if (EPI == 1) {
                Cout[(size_t)r * N + c] = res[(size_t)r * N + c] + val;
            } else {
                Cout[(size_t)r * N + c] = 0.5f * val * (1.0f + erff(val * 0.70710678118f));
            }
        }
    }
}

// ---------------- 3D RoPE: rotate Q in place, rotate K and write K^T [bh][d][s] ----------------
__global__ __launch_bounds__(256) void rope_kernel(const float* __restrict__ coords,
                                                   float* __restrict__ q,
                                                   const float* __restrict__ kin,
                                                   float* __restrict__ kT) {
    __shared__ float tile[64][97];   // pad: conflict-free column reads in transpose phase
    __shared__ float cst[64][49];    // pad 49: conflict-free when lanes vary in s
    __shared__ float snt[64][49];
    int nblk = NS / 64;
    int bh = blockIdx.x / nblk;
    int s0 = (blockIdx.x % nblk) * 64;
    int b_ = bh / NH;
    int t = threadIdx.x;
    // trig table: 64 s-rows x (3 axes x 16 freqs)
    for (int i = t; i < 64 * 48; i += 256) {
        int sl = i / 48, f = i - sl * 48;
        int axis = f >> 4, j = f & 15;
        float c = coords[(size_t)(b_ * NS + s0 + sl) * 3 + axis];
        float ang = c * powf(10000.0f, -(float)j * (1.0f / 16.0f));
        float sv, cv;
        sincosf(ang, &sv, &cv);
        cst[sl][f] = cv; snt[sl][f] = sv;
    }
    // ---- Q: load tile, rotate, write back in place (coalesced along d) ----
    float* qp = q + (size_t)(bh * NS + s0) * NDH;
    for (int i = t; i < 64 * NDH; i += 256) tile[i / NDH][i % NDH] = qp[i];
    __syncthreads();
    #pragma unroll
    for (int e = 0; e < 24; ++e) {
        int i = t + e * 256;
        int sl = i / NDH, dd = i % NDH;
        int axis = dd >> 5, r = dd & 31, j = r & 15;
        float x1 = tile[sl][(axis << 5) + j];
        float x2 = tile[sl][(axis << 5) + 16 + j];
        float cv = cst[sl][(axis << 4) + j], sv = snt[sl][(axis << 4) + j];
        qp[i] = (r < 16) ? (x1 * cv - x2 * sv) : (x1 * sv + x2 * cv);
    }
    __syncthreads();
    // ---- K: load tile, rotate, write transposed [d][s] (coalesced along s) ----
    const float* kp = kin + (size_t)(bh * NS + s0) * NDH;
    for (int i = t; i < 64 * NDH; i += 256) tile[i / NDH][i % NDH] = kp[i];
    __syncthreads();
    float* ktp = kT + (size_t)bh * NDH * NS;
    #pragma unroll
    for (int e = 0; e < 24; ++e) {
        int i = t + e * 256;
        int dd = i >> 6, sl = i & 63;
        int axis = dd >> 5, r = dd & 31, j = r & 15;
        float x1 = tile[sl][(axis << 5) + j];
        float x2 = tile[sl][(axis << 5) + 16 + j];
        float cv = cst[sl][(axis << 4) + j], sv = snt[sl][(axis << 4) + j];
        float val = (r < 16) ? (x1 * cv - x2 * sv) : (x1 * sv + x2 * cv);
        ktp[(size_t)dd * NS + s0 + sl] = val;
    }
}

// ---------------- causal flash attention: 1 wave handles 4 query rows ----------------
__global__ __launch_bounds__(64) void attn_kernel(const float* __restrict__ q,
                                                  const float* __restrict__ kT,
                                                  const float* __restrict__ v,
                                                  float* __restrict__ out) {
    const float scale = 0.1020620726159658f;   // 1/sqrt(96)
    int nblk = NS / 4;
    int bh = blockIdx.x / nblk;
    int s0 = (blockIdx.x % nblk) * 4;
    int l = threadIdx.x;
    __shared__ float qs[4][NDH];
    __shared__ float ps[4][64];
    const float* qb = q + (size_t)(bh * NS + s0) * NDH;
    for (int i = l; i < 4 * NDH; i += 64) qs[i / NDH][i % NDH] = qb[i];
    __syncthreads();
    const float* ktb = kT + (size_t)bh * NDH * NS;
    const float* vb  = v  + (size_t)bh * NS * NDH;
    float m[4], ell[4] = {0, 0, 0, 0}, a0[4] = {0, 0, 0, 0}, a1[4] = {0, 0, 0, 0};
    m[0] = m[1] = m[2] = m[3] = -INFINITY;
    int smax = s0 + 3;
    for (int k0 = 0; k0 <= smax; k0 += 64) {
        // scores: lane l owns key k0+l, iterate d reading K^T coalesced
        float sc[4] = {0, 0, 0, 0};
        const float* kp = ktb + k0 + l;
        #pragma unroll 8
        for (int d0 = 0; d0 < NDH; d0 += 4) {
            float k0v = kp[(size_t)(d0 + 0) * NS];
            float k1v = kp[(size_t)(d0 + 1) * NS];
            float k2v = kp[(size_t)(d0 + 2) * NS];
            float k3v = kp[(size_t)(d0 + 3) * NS];
            #pragma unroll
            for (int r = 0; r < 4; ++r) {
                const float4 qv = *(const float4*)&qs[r][d0];
                sc[r] += qv.x * k0v + qv.y * k1v + qv.z * k2v + qv.w * k3v;
            }
        }
        int kk = k0 + l;
        #pragma unroll
        for (int r = 0; r < 4; ++r) {
            float sr = (kk <= s0 + r) ? sc[r] * scale : -INFINITY;
            float cm = sr;
            #pragma unroll
            for (int o = 32; o > 0; o >>= 1) cm = fmaxf(cm, __shfl_xor(cm, o));
            float mn = fmaxf(m[r], cm);               // always finite: lane 0 valid
            float al = expf(m[r] - mn);               // first chunk: exp(-inf)=0
            float p  = expf(sr - mn);                 // masked: exp(-inf)=0
            float psum = p;
            #pragma unroll
            for (int o = 32; o > 0; o >>= 1) psum += __shfl_xor(psum, o);
            ell[r] = ell[r] * al + psum;
            m[r] = mn;
            a0[r] *= al; a1[r] *= al;
            ps[r][l] = p;
        }
        __syncthreads();
        // PV: all lanes cooperate; lane owns output dims d=l and d=64+l (l<32)
        int jc = smax - k0 + 1; if (jc > 64) jc = 64;
        const float* vp = vb + (size_t)k0 * NDH;
        for (int j = 0; j < jc; ++j) {
            float p0 = ps[0][j], p1 = ps[1][j], p2 = ps[2][j], p3 = ps[3][j];
            float vv0 = vp[(size_t)j * NDH + l];
            a0[0] += p0 * vv0; a0[1] += p1 * vv0; a0[2] += p2 * vv0; a0[3] += p3 * vv0;
            if (l < 32) {
                float vv1 = vp[(size_t)j * NDH + 64 + l];
                a1[0] += p0 * vv1; a1[1] += p1 * vv1; a1[2] += p2 * vv1; a1[3] += p3 * vv1;
            }
        }
        __syncthreads();
    }
    int b_ = bh / NH, hh = bh % NH;
    float* ob = out + (size_t)(b_ * NS + s0) * ND + hh * NDH;
    #pragma unroll
    for (int r = 0; r < 4; ++r) {
        float inv = 1.0f / ell[r];
        ob[(size_t)r * ND + l] = a0[r] * inv;
        if (l < 32) ob[(size_t)r * ND + 64 + l] = a1[r] * inv;
    }
}

extern "C" void kernel_launch(void* const* d_in, const int* in_sizes, int n_in,
                              void* d_out, int out_size, void* d_ws, size_t ws_size,
                              hipStream_t stream) {
    const float* src    = (const float*)d_in[0];
    const float* coords = (const float*)d_in[1];
    // d_in[2] = causal_mask (unused: causality computed analytically)
    const float* n1g  = (const float*)d_in[3];
    const float* n1b  = (const float*)d_in[4];
    const float* qkvw = (const float*)d_in[5];
    const float* qkvb = (const float*)d_in[6];
    const float* projw= (const float*)d_in[7];
    const float* projb= (const float*)d_in[8];
    const float* n2g  = (const float*)d_in[9];
    const float* n2b  = (const float*)d_in[10];
    const float* fc1w = (const float*)d_in[11];
    const float* fc1b = (const float*)d_in[12];
    const float* fc2w = (const float*)d_in[13];
    const float* fc2b = (const float*)d_in[14];
    float* out = (float*)d_out;
    float* ws  = (float*)d_ws;

    const size_t N1 = (size_t)NROWS * ND;    // 6.29M floats
    float* x    = ws;                        // residual-1 output, live to end
    float* xn   = ws + N1;                   // LN1 out; later reused as kT, then y1
    float* qb   = ws + 2 * N1;
    float* kb   = ws + 3 * N1;
    float* vb   = ws + 4 * N1;
    float* ao   = ws + 5 * N1;               // attention out
    float* hbuf = ws + 2 * N1;               // fc1 out (4*N1), reuses q/k/v/ao region
    float* kT   = xn;
    float* y1   = xn;

    // 1) LN1
    ln_kernel<<<NROWS, 256, 0, stream>>>(src, n1g, n1b, xn);
    // 2) QKV GEMM + bias, scatter to [B,H,S,DH]
    gemm_kernel<0><<<(NROWS / 64) * (3 * ND / 64), 256, 0, stream>>>(
        xn, qkvw, qkvb, nullptr, nullptr, qb, kb, vb, NROWS, 3 * ND, ND);
    // 3) RoPE on q (in place) and k (-> kT transposed)
    rope_kernel<<<NB * NH * (NS / 64), 256, 0, stream>>>(coords, qb, kb, kT);
    // 4) causal flash attention
    attn_kernel<<<NB * NH * (NS / 4), 64, 0, stream>>>(qb, kT, vb, ao);
    // 5) proj GEMM + bias + residual(src) -> x
    gemm_kernel<1><<<(NROWS / 64) * (ND / 64), 256, 0, stream>>>(
        ao, projw, projb, x, src, nullptr, nullptr, nullptr, NROWS, ND, ND);
    // 6) LN2
    ln_kernel<<<NROWS, 256, 0, stream>>>(x, n2g, n2b, y1);
    // 7) FC1 GEMM + bias + exact GELU
    gemm_kernel<2><<<(NROWS / 64) * (NHID / 64), 256, 0, stream>>>(
        y1, fc1w, fc1b, hbuf, nullptr, nullptr, nullptr, nullptr, NROWS, NHID, ND);
    // 8) FC2 GEMM + bias + residual(x) -> out
    gemm_kernel<1><<<(NROWS / 64) * (ND / 64), 256, 0, stream>>>(
        hbuf, fc2w, fc2b, out, x, nullptr, nullptr, nullptr, NROWS, ND, NHID);
}

// Round 4
// 1811.952 us; speedup vs baseline: 2.4201x; 2.4201x over previous
//
#include <hip/hip_runtime.h>
#include <hip/hip_bf16.h>
#include <math.h>

#define NB 4
#define NS 2048
#define ND 768
#define NH 8
#define NDH 96
#define NHID 3072
#define NROWS (NB*NS)

typedef __attribute__((ext_vector_type(8))) short bf16x8;
typedef __attribute__((ext_vector_type(4))) float f32x4;

// ---------------- block-wide sum over 256 threads ----------------
static __device__ __forceinline__ float block_sum256(float v) {
    __shared__ float red[4];
    #pragma unroll
    for (int o = 32; o > 0; o >>= 1) v += __shfl_down(v, o);
    int w = threadIdx.x >> 6;
    __syncthreads();
    if ((threadIdx.x & 63) == 0) red[w] = v;
    __syncthreads();
    return red[0] + red[1] + red[2] + red[3];
}

// ---------------- LayerNorm: one block per row of 768 ----------------
__global__ __launch_bounds__(256) void ln_kernel(const float* __restrict__ in,
                                                 const float* __restrict__ g,
                                                 const float* __restrict__ bta,
                                                 float* __restrict__ out) {
    int row = blockIdx.x;
    const float* x = in + (size_t)row * ND;
    int t = threadIdx.x;
    float v0 = x[t], v1 = x[t + 256], v2 = x[t + 512];
    float mu = block_sum256(v0 + v1 + v2) * (1.0f / ND);
    float d0 = v0 - mu, d1 = v1 - mu, d2 = v2 - mu;
    float var = block_sum256(d0*d0 + d1*d1 + d2*d2) * (1.0f / ND);
    float rs = rsqrtf(var + 1e-6f);
    float* o = out + (size_t)row * ND;
    o[t]       = d0 * rs * g[t]       + bta[t];
    o[t + 256] = d1 * rs * g[t + 256] + bta[t + 256];
    o[t + 512] = d2 * rs * g[t + 512] + bta[t + 512];
}

// ---------------- f32 tiled GEMM, 64x64x16, 256 threads, 4x4/thread ----------------
// EPI: 0 = QKV scatter (+bias), 1 = +bias +residual, 2 = +bias +exact GELU
template<int EPI>
__global__ __launch_bounds__(256) void gemm_kernel(
        const float* __restrict__ A, const float* __restrict__ Bw,
        const float* __restrict__ bias, float* __restrict__ Cout,
        const float* __restrict__ res,
        float* __restrict__ qo, float* __restrict__ ko, float* __restrict__ vo,
        int M, int N, int K) {
    __shared__ float As[16][68];
    __shared__ float Bs[16][64];
    int nb = N >> 6;
    int bx = blockIdx.x % nb, by = blockIdx.x / nb;
    int t = threadIdx.x;
    int tx = t & 15, ty = t >> 4;
    int arow = t >> 2,  ac4 = (t & 3) << 2;
    int brow = t >> 4,  bc4 = (t & 15) << 2;
    const float* Ab = A + (size_t)(by * 64) * K;
    const float* Bb = Bw + bx * 64;
    float acc[4][4] = {};
    for (int k0 = 0; k0 < K; k0 += 16) {
        float4 a4 = *(const float4*)&Ab[(size_t)arow * K + k0 + ac4];
        float4 b4 = *(const float4*)&Bb[(size_t)(k0 + brow) * N + bc4];
        __syncthreads();
        As[ac4 + 0][arow] = a4.x; As[ac4 + 1][arow] = a4.y;
        As[ac4 + 2][arow] = a4.z; As[ac4 + 3][arow] = a4.w;
        *(float4*)&Bs[brow][bc4] = b4;
        __syncthreads();
        #pragma unroll
        for (int kk = 0; kk < 16; ++kk) {
            float4 av = *(const float4*)&As[kk][ty << 2];
            float4 bv = *(const float4*)&Bs[kk][tx << 2];
            float aa[4] = {av.x, av.y, av.z, av.w};
            float bb[4] = {bv.x, bv.y, bv.z, bv.w};
            #pragma unroll
            for (int i = 0; i < 4; ++i)
                #pragma unroll
                for (int j = 0; j < 4; ++j)
                    acc[i][j] += aa[i] * bb[j];
        }
    }
    int r0 = (by << 6) + (ty << 2), c0 = (bx << 6) + (tx << 2);
    #pragma unroll
    for (int i = 0; i < 4; ++i) {
        int r = r0 + i;
        #pragma unroll
        for (int j = 0; j < 4; ++j) {
            int c = c0 + j;
            float val = acc[i][j] + bias[c];
            if (EPI == 0) {
                int which = c / ND;
                int cc = c - which * ND;
                int hh = cc / NDH, dd = cc - hh * NDH;
                int b_ = r >> 11, s_ = r & (NS - 1);
                float* dst = (which == 0) ? qo : (which == 1) ? ko : vo;
                dst[(size_t)((b_ * NH + hh) * NS + s_) * NDH + dd] = val;
            } else if (EPI == 1) {
                Cout[(size_t)r * N + c] = res[(size_t)r * N + c] + val;
            } else {
                Cout[(size_t)r * N + c] = 0.5f * val * (1.0f + erff(val * 0.70710678118f));
            }
        }
    }
}

// ---------------- 3D RoPE: q,k f32 -> rotated bf16 (row-major), v f32 -> bf16 ----------------
__global__ __launch_bounds__(256) void rope_bf16_kernel(const float* __restrict__ coords,
                                                        const float* __restrict__ qin,
                                                        const float* __restrict__ kin,
                                                        const float* __restrict__ vin,
                                                        __hip_bfloat16* __restrict__ qo,
                                                        __hip_bfloat16* __restrict__ ko,
                                                        __hip_bfloat16* __restrict__ vo) {
    __shared__ float tile[64][97];
    __shared__ float cst[64][49];
    __shared__ float snt[64][49];
    int nblk = NS / 64;
    int bh = blockIdx.x / nblk;
    int s0 = (blockIdx.x % nblk) * 64;
    int b_ = bh / NH;
    int t = threadIdx.x;
    // trig table: 64 s-rows x (3 axes x 16 freqs)
    for (int i = t; i < 64 * 48; i += 256) {
        int sl = i / 48, f = i - sl * 48;
        int axis = f >> 4, j = f & 15;
        float c = coords[(size_t)(b_ * NS + s0 + sl) * 3 + axis];
        float ang = c * powf(10000.0f, -(float)j * (1.0f / 16.0f));
        float sv, cv;
        sincosf(ang, &sv, &cv);
        cst[sl][f] = cv; snt[sl][f] = sv;
    }
    size_t base = (size_t)(bh * NS + s0) * NDH;
    // ---- Q ----
    const float* qp = qin + base;
    for (int i = t; i < 64 * NDH; i += 256) tile[i / NDH][i % NDH] = qp[i];
    __syncthreads();
    #pragma unroll
    for (int e = 0; e < 24; ++e) {
        int i = t + e * 256;
        int sl = i / NDH, dd = i % NDH;
        int axis = dd >> 5, r = dd & 31, j = r & 15;
        float x1 = tile[sl][(axis << 5) + j];
        float x2 = tile[sl][(axis << 5) + 16 + j];
        float cv = cst[sl][(axis << 4) + j], sv = snt[sl][(axis << 4) + j];
        qo[base + i] = __float2bfloat16((r < 16) ? (x1 * cv - x2 * sv) : (x1 * sv + x2 * cv));
    }
    __syncthreads();
    // ---- K ----
    const float* kp = kin + base;
    for (int i = t; i < 64 * NDH; i += 256) tile[i / NDH][i % NDH] = kp[i];
    __syncthreads();
    #pragma unroll
    for (int e = 0; e < 24; ++e) {
        int i = t + e * 256;
        int sl = i / NDH, dd = i % NDH;
        int axis = dd >> 5, r = dd & 31, j = r & 15;
        float x1 = tile[sl][(axis << 5) + j];
        float x2 = tile[sl][(axis << 5) + 16 + j];
        float cv = cst[sl][(axis << 4) + j], sv = snt[sl][(axis << 4) + j];
        ko[base + i] = __float2bfloat16((r < 16) ? (x1 * cv - x2 * sv) : (x1 * sv + x2 * cv));
    }
    // ---- V convert ----
    const float* vp = vin + base;
    #pragma unroll
    for (int e = 0; e < 24; ++e) {
        int i = t + e * 256;
        vo[base + i] = __float2bfloat16(vp[i]);
    }
}

// ---------------- MFMA bf16 causal flash attention ----------------
// block = 1 bh x 128 q-rows; 4 waves x 32 rows; KV chunks of 64.
__global__ __launch_bounds__(256) void attn_mfma(const __hip_bfloat16* __restrict__ q,
                                                 const __hip_bfloat16* __restrict__ k,
                                                 const __hip_bfloat16* __restrict__ v,
                                                 float* __restrict__ out) {
    const float scale = 0.1020620726159658f;   // 1/sqrt(96)
    __shared__ __hip_bfloat16 Ks[64][104];     // K chunk row-major, padded (2-way max)
    __shared__ __hip_bfloat16 Vt[96][72];      // V chunk transposed [d][kv]
    __shared__ __hip_bfloat16 Ps[4][32][72];   // per-wave P tile
    int bx = blockIdx.x;
    int bh = bx >> 4, qb = bx & 15;
    int q0 = qb << 7;
    int t = threadIdx.x, w = t >> 6, l = t & 63;
    int lr = l & 15, lg = l >> 4;
    int qw = q0 + (w << 5);
    const __hip_bfloat16* qg = q + (size_t)bh * NS * NDH;
    const __hip_bfloat16* kg = k + (size_t)bh * NS * NDH;
    const __hip_bfloat16* vg = v + (size_t)bh * NS * NDH;

    // Q fragments: A[16q][32d] per (mt,ks): lane -> row lr, k = lg*8..+7
    bf16x8 qa[2][3];
    #pragma unroll
    for (int mt = 0; mt < 2; ++mt)
        #pragma unroll
        for (int ks = 0; ks < 3; ++ks)
            qa[mt][ks] = *(const bf16x8*)&qg[(size_t)(qw + mt*16 + lr) * NDH + ks*32 + lg*8];

    f32x4 acco[2][6];
    #pragma unroll
    for (int mt = 0; mt < 2; ++mt)
        #pragma unroll
        for (int dt = 0; dt < 6; ++dt)
            acco[mt][dt] = (f32x4){0.f, 0.f, 0.f, 0.f};
    float mrow[2][4], lsum[2][4];
    #pragma unroll
    for (int mt = 0; mt < 2; ++mt)
        #pragma unroll
        for (int r = 0; r < 4; ++r) { mrow[mt][r] = -INFINITY; lsum[mt][r] = 0.f; }

    int nch = (q0 + 128) >> 6;   // causal: chunks up to block's max row
    for (int c = 0; c < nch; ++c) {
        int kv0 = c << 6;
        __syncthreads();
        // stage K chunk: 64 rows x 96 el, 16B pieces
        #pragma unroll
        for (int i = 0; i < 3; ++i) {
            int cc = t + i * 256;
            int row = cc / 12, off = (cc % 12) * 8;
            *(bf16x8*)&Ks[row][off] = *(const bf16x8*)&kg[(size_t)(kv0 + row) * NDH + off];
        }
        // stage V transposed: thread t -> row kr, 24 d-elements
        {
            int kr = t >> 2, dp = (t & 3) * 24;
            const __hip_bfloat16* vr = &vg[(size_t)(kv0 + kr) * NDH + dp];
            #pragma unroll
            for (int j = 0; j < 24; ++j) Vt[dp + j][kr] = vr[j];
        }
        __syncthreads();
        // QK^T: S[32q][64kv] per wave
        f32x4 s[2][4];
        #pragma unroll
        for (int mt = 0; mt < 2; ++mt)
            #pragma unroll
            for (int nt = 0; nt < 4; ++nt)
                s[mt][nt] = (f32x4){0.f, 0.f, 0.f, 0.f};
        #pragma unroll
        for (int ks = 0; ks < 3; ++ks) {
            #pragma unroll
            for (int nt = 0; nt < 4; ++nt) {
                bf16x8 kb_ = *(const bf16x8*)&Ks[nt*16 + lr][ks*32 + lg*8];
                #pragma unroll
                for (int mt = 0; mt < 2; ++mt)
                    s[mt][nt] = __builtin_amdgcn_mfma_f32_16x16x32_bf16(qa[mt][ks], kb_, s[mt][nt], 0, 0, 0);
            }
        }
        // online softmax; C layout: row = lg*4+r (+mt*16), col = lr (+nt*16)
        #pragma unroll
        for (int mt = 0; mt < 2; ++mt) {
            float al[4];
            #pragma unroll
            for (int r = 0; r < 4; ++r) {
                int qrow = qw + mt*16 + lg*4 + r;
                float mx = -INFINITY;
                #pragma unroll
                for (int nt = 0; nt < 4; ++nt) {
                    int col = kv0 + nt*16 + lr;
                    float sc = (col <= qrow) ? s[mt][nt][r] * scale : -INFINITY;
                    s[mt][nt][r] = sc;
                    mx = fmaxf(mx, sc);
                }
                #pragma unroll
                for (int o = 1; o < 16; o <<= 1) mx = fmaxf(mx, __shfl_xor(mx, o));
                float mn = fmaxf(mrow[mt][r], mx);
                al[r] = __expf(mrow[mt][r] - mn);   // first chunk: exp(-inf)=0
                mrow[mt][r] = mn;
                float rs = 0.f;
                #pragma unroll
                for (int nt = 0; nt < 4; ++nt) {
                    float p = __expf(s[mt][nt][r] - mn);
                    s[mt][nt][r] = p;
                    rs += p;
                }
                #pragma unroll
                for (int o = 1; o < 16; o <<= 1) rs += __shfl_xor(rs, o);
                lsum[mt][r] = lsum[mt][r] * al[r] + rs;
                #pragma unroll
                for (int nt = 0; nt < 4; ++nt)
                    Ps[w][mt*16 + lg*4 + r][nt*16 + lr] = __float2bfloat16(s[mt][nt][r]);
            }
            #pragma unroll
            for (int dt = 0; dt < 6; ++dt)
                #pragma unroll
                for (int r = 0; r < 4; ++r)
                    acco[mt][dt][r] *= al[r];
        }
        // PV: O[32q][96d] += P[32x64] x V[64x96]  (B from Vt, A from Ps)
        #pragma unroll
        for (int ks = 0; ks < 2; ++ks) {
            bf16x8 pa[2];
            #pragma unroll
            for (int mt = 0; mt < 2; ++mt)
                pa[mt] = *(const bf16x8*)&Ps[w][mt*16 + lr][ks*32 + lg*8];
            #pragma unroll
            for (int dt = 0; dt < 6; ++dt) {
                bf16x8 vb_ = *(const bf16x8*)&Vt[dt*16 + lr][ks*32 + lg*8];
                #pragma unroll
                for (int mt = 0; mt < 2; ++mt)
                    acco[mt][dt] = __builtin_amdgcn_mfma_f32_16x16x32_bf16(pa[mt], vb_, acco[mt][dt], 0, 0, 0);
            }
        }
    }
    // epilogue: divide by l, write f32 to [B][S][768]
    int b_ = bh >> 3, hh = bh & 7;
    #pragma unroll
    for (int mt = 0; mt < 2; ++mt) {
        float inv[4];
        #pragma unroll
        for (int r = 0; r < 4; ++r) inv[r] = 1.0f / lsum[mt][r];
        #pragma unroll
        for (int dt = 0; dt < 6; ++dt)
            #pragma unroll
            for (int r = 0; r < 4; ++r) {
                int row = qw + mt*16 + lg*4 + r;
                out[((size_t)(b_ * NS + row)) * ND + hh * NDH + dt*16 + lr] = acco[mt][dt][r] * inv[r];
            }
    }
}

extern "C" void kernel_launch(void* const* d_in, const int* in_sizes, int n_in,
                              void* d_out, int out_size, void* d_ws, size_t ws_size,
                              hipStream_t stream) {
    const float* src    = (const float*)d_in[0];
    const float* coords = (const float*)d_in[1];
    const float* n1g  = (const float*)d_in[3];
    const float* n1b  = (const float*)d_in[4];
    const float* qkvw = (const float*)d_in[5];
    const float* qkvb = (const float*)d_in[6];
    const float* projw= (const float*)d_in[7];
    const float* projb= (const float*)d_in[8];
    const float* n2g  = (const float*)d_in[9];
    const float* n2b  = (const float*)d_in[10];
    const float* fc1w = (const float*)d_in[11];
    const float* fc1b = (const float*)d_in[12];
    const float* fc2w = (const float*)d_in[13];
    const float* fc2b = (const float*)d_in[14];
    float* out = (float*)d_out;
    float* ws  = (float*)d_ws;

    const size_t N1 = (size_t)NROWS * ND;    // 6.29M floats
    float* x    = ws;                        // residual-1, live to end
    float* xn   = ws + N1;                   // LN1 out (f32); later qbf/kbf (bf16)
    float* qf   = ws + 2 * N1;               // QKV q f32; dead after rope
    float* kf   = ws + 3 * N1;               // QKV k f32; dead after rope -> ao
    float* vf   = ws + 4 * N1;               // QKV v f32; dead after rope
    float* w5   = ws + 5 * N1;               // vbf during attn; y1 after proj
    __hip_bfloat16* qbf = (__hip_bfloat16*)xn;          // N1 bf16
    __hip_bfloat16* kbf = ((__hip_bfloat16*)xn) + N1;   // N1 bf16 (fits: xn = N1 f32)
    __hip_bfloat16* vbf = (__hip_bfloat16*)w5;          // N1 bf16
    float* ao   = kf;                        // attention out (f32)
    float* y1   = w5;                        // LN2 out
    float* hbuf = ws + N1;                   // fc1 out: slots 1-4 (all dead by then)

    // 1) LN1
    ln_kernel<<<NROWS, 256, 0, stream>>>(src, n1g, n1b, xn);
    // 2) QKV GEMM + bias, scatter q/k/v f32 [bh][s][dh]
    gemm_kernel<0><<<(NROWS / 64) * (3 * ND / 64), 256, 0, stream>>>(
        xn, qkvw, qkvb, nullptr, nullptr, qf, kf, vf, NROWS, 3 * ND, ND);
    // 3) RoPE -> bf16 q,k (row-major) + bf16 v
    rope_bf16_kernel<<<NB * NH * (NS / 64), 256, 0, stream>>>(coords, qf, kf, vf, qbf, kbf, vbf);
    // 4) MFMA flash attention -> ao f32 [B,S,D]
    attn_mfma<<<NB * NH * (NS / 128), 256, 0, stream>>>(qbf, kbf, vbf, ao);
    // 5) proj GEMM + bias + residual(src) -> x
    gemm_kernel<1><<<(NROWS / 64) * (ND / 64), 256, 0, stream>>>(
        ao, projw, projb, x, src, nullptr, nullptr, nullptr, NROWS, ND, ND);
    // 6) LN2
    ln_kernel<<<NROWS, 256, 0, stream>>>(x, n2g, n2b, y1);
    // 7) FC1 GEMM + bias + exact GELU
    gemm_kernel<2><<<(NROWS / 64) * (NHID / 64), 256, 0, stream>>>(
        y1, fc1w, fc1b, hbuf, nullptr, nullptr, nullptr, nullptr, NROWS, NHID, ND);
    // 8) FC2 GEMM + bias + residual(x) -> out
    gemm_kernel<1><<<(NROWS / 64) * (ND / 64), 256, 0, stream>>>(
        hbuf, fc2w, fc2b, out, x, nullptr, nullptr, nullptr, NROWS, ND, NHID);
}

// Round 5
// 546.617 us; speedup vs baseline: 8.0222x; 3.3149x over previous
//
#include <hip/hip_runtime.h>
#include <hip/hip_bf16.h>
#include <math.h>

#define NB 4
#define NS 2048
#define ND 768
#define NH 8
#define NDH 96
#define NHID 3072
#define NROWS (NB*NS)

typedef __attribute__((ext_vector_type(8))) short bf16x8;
typedef __attribute__((ext_vector_type(4))) float f32x4;

// async global->LDS, 16B per lane. LDS dest must be wave-uniform base (HW adds lane*16).
#define GLOAD16(gp, lp)                                                          \
    __builtin_amdgcn_global_load_lds(                                            \
        (__attribute__((address_space(1))) void*)(unsigned long long)(gp),       \
        (__attribute__((address_space(3))) void*)(unsigned long long)(lp), 16, 0, 0)

// ---------------- block-wide sum over 256 threads ----------------
static __device__ __forceinline__ float block_sum256(float v) {
    __shared__ float red[4];
    #pragma unroll
    for (int o = 32; o > 0; o >>= 1) v += __shfl_down(v, o);
    int w = threadIdx.x >> 6;
    __syncthreads();
    if ((threadIdx.x & 63) == 0) red[w] = v;
    __syncthreads();
    return red[0] + red[1] + red[2] + red[3];
}

// ---------------- LayerNorm: f32 in -> bf16 out ----------------
__global__ __launch_bounds__(256) void ln_bf16_kernel(const float* __restrict__ in,
                                                      const float* __restrict__ g,
                                                      const float* __restrict__ bta,
                                                      __hip_bfloat16* __restrict__ out) {
    int row = blockIdx.x;
    const float* x = in + (size_t)row * ND;
    int t = threadIdx.x;
    float v0 = x[t], v1 = x[t + 256], v2 = x[t + 512];
    float mu = block_sum256(v0 + v1 + v2) * (1.0f / ND);
    float d0 = v0 - mu, d1 = v1 - mu, d2 = v2 - mu;
    float var = block_sum256(d0*d0 + d1*d1 + d2*d2) * (1.0f / ND);
    float rs = rsqrtf(var + 1e-6f);
    __hip_bfloat16* o = out + (size_t)row * ND;
    o[t]       = __float2bfloat16(d0 * rs * g[t]       + bta[t]);
    o[t + 256] = __float2bfloat16(d1 * rs * g[t + 256] + bta[t + 256]);
    o[t + 512] = __float2bfloat16(d2 * rs * g[t + 512] + bta[t + 512]);
}

// ---------------- weight transpose+convert: w[K][N] f32 -> wT[N][K] bf16 ----------------
__global__ __launch_bounds__(256) void wtrans_kernel(const float* __restrict__ w,
                                                     __hip_bfloat16* __restrict__ wT,
                                                     int K, int N) {
    __shared__ float tile[32][33];
    int nb = N >> 5;
    int k0 = (blockIdx.x / nb) << 5, n0 = (blockIdx.x % nb) << 5;
    int t = threadIdx.x;
    int rr = t >> 5, cc = t & 31;
    #pragma unroll
    for (int j = 0; j < 4; ++j)
        tile[rr + j*8][cc] = w[(size_t)(k0 + rr + j*8) * N + n0 + cc];
    __syncthreads();
    #pragma unroll
    for (int j = 0; j < 4; ++j)
        wT[(size_t)(n0 + rr + j*8) * K + k0 + cc] = __float2bfloat16(tile[cc][rr + j*8]);
}

// ---------------- bf16 MFMA GEMM: C[M][N] = A[M][K] * BT[N][K]^T ----------------
// 128x128 tile, BK=64, 256 thr (4 waves 2x2), global_load_lds w/ XOR-swizzled source.
// EPI: 0 = +bias, scatter bf16 q/k/v [bh][s][dh]; 1 = +bias+res -> f32; 2 = +bias+GELU -> bf16
template<int EPI>
__global__ __launch_bounds__(256) void gemm_mfma(
        const __hip_bfloat16* __restrict__ A, const __hip_bfloat16* __restrict__ BT,
        const float* __restrict__ bias, int M, int N, int K,
        float* __restrict__ Cf, const float* __restrict__ res,
        __hip_bfloat16* __restrict__ Cb,
        __hip_bfloat16* __restrict__ qo, __hip_bfloat16* __restrict__ ko,
        __hip_bfloat16* __restrict__ vo) {
    __shared__ __attribute__((aligned(16))) __hip_bfloat16 As[128][64];
    __shared__ __attribute__((aligned(16))) __hip_bfloat16 Bs[128][64];
    int bx = blockIdx.x, by = blockIdx.y;
    int t = threadIdx.x, w = t >> 6, l = t & 63;
    int lr = l & 15, lg = l >> 4;
    int wr = w >> 1, wc = w & 1;

    // staging: chunk (w,i) covers LDS bytes [(i*4+w)*1024, +1024); lane lands at +l*16
    int off  = w * 1024 + l * 16;
    int srow = off >> 7;              // tile row (128 B per row)
    int scol = off & 127;             // landing byte col within row
    int scolS = scol ^ ((srow & 7) << 4);   // inverse-swizzled SOURCE col (T2, rule #21)
    const char* ap = (const char*)(A  + (size_t)(by * 128 + srow) * K) + scolS;
    const char* bp = (const char*)(BT + (size_t)(bx * 128 + srow) * K) + scolS;
    size_t rstep = (size_t)32 * K * 2;      // i -> i+1 : +32 rows
    char* asl = ((char*)As) + w * 1024;     // wave-uniform LDS base, i=0
    char* bsl = ((char*)Bs) + w * 1024;

    f32x4 acc[4][4];
    #pragma unroll
    for (int i = 0; i < 4; ++i)
        #pragma unroll
        for (int j = 0; j < 4; ++j) acc[i][j] = (f32x4){0.f, 0.f, 0.f, 0.f};

    int mask = (lr & 7) << 4;               // swizzled READ xor (row&7 == lr&7)
    const char* asb = (const char*)As;
    const char* bsb = (const char*)Bs;

    for (int k0 = 0; k0 < K; k0 += 64) {
        __syncthreads();                     // prior compute done reading LDS
        #pragma unroll
        for (int i = 0; i < 4; ++i) {
            GLOAD16(ap + i * rstep, asl + i * 4096);
            GLOAD16(bp + i * rstep, bsl + i * 4096);
        }
        ap += 128; bp += 128;
        __syncthreads();                     // staging drained (vmcnt(0) at barrier)
        #pragma unroll
        for (int ks = 0; ks < 2; ++ks) {
            bf16x8 a[4], b[4];
            #pragma unroll
            for (int x = 0; x < 4; ++x) {
                int ra = (wr << 6) + x*16 + lr;
                int rb = (wc << 6) + x*16 + lr;
                int cb = ((ks * 64 + lg * 16) ^ mask);
                a[x] = *(const bf16x8*)(asb + ra * 128 + cb);
                b[x] = *(const bf16x8*)(bsb + rb * 128 + cb);
            }
            #pragma unroll
            for (int mt = 0; mt < 4; ++mt)
                #pragma unroll
                for (int nt = 0; nt < 4; ++nt)
                    acc[mt][nt] = __builtin_amdgcn_mfma_f32_16x16x32_bf16(a[mt], b[nt], acc[mt][nt], 0, 0, 0);
        }
    }

    // epilogue: C row = by*128 + wr*64 + mt*16 + lg*4 + rr; col = bx*128 + wc*64 + nt*16 + lr
    int rbase = by * 128 + (wr << 6) + lg * 4;
    int cbase = bx * 128 + (wc << 6) + lr;
    #pragma unroll
    for (int nt = 0; nt < 4; ++nt) {
        int gc = cbase + nt * 16;
        float bv = bias[gc];
        #pragma unroll
        for (int mt = 0; mt < 4; ++mt) {
            #pragma unroll
            for (int rr = 0; rr < 4; ++rr) {
                int gr = rbase + mt * 16 + rr;
                float val = acc[mt][nt][rr] + bv;
                if (EPI == 0) {
                    int which = gc / ND;
                    int ccc = gc - which * ND;
                    int hh = ccc / NDH, dd = ccc - hh * NDH;
                    int b_ = gr >> 11, s_ = gr & (NS - 1);
                    __hip_bfloat16* dst = (which == 0) ? qo : (which == 1) ? ko : vo;
                    dst[(size_t)((b_ * NH + hh) * NS + s_) * NDH + dd] = __float2bfloat16(val);
                } else if (EPI == 1) {
                    Cf[(size_t)gr * N + gc] = res[(size_t)gr * N + gc] + val;
                } else {
                    Cb[(size_t)gr * N + gc] =
                        __float2bfloat16(0.5f * val * (1.0f + erff(val * 0.70710678118f)));
                }
            }
        }
    }
}

// ---------------- 3D RoPE: rotate q,k bf16 in place ----------------
__global__ __launch_bounds__(256) void rope_bf16_kernel(const float* __restrict__ coords,
                                                        __hip_bfloat16* __restrict__ q,
                                                        __hip_bfloat16* __restrict__ k) {
    __shared__ float tile[64][97];
    __shared__ float cst[64][49];
    __shared__ float snt[64][49];
    int nblk = NS / 64;
    int bh = blockIdx.x / nblk;
    int s0 = (blockIdx.x % nblk) * 64;
    int b_ = bh / NH;
    int t = threadIdx.x;
    for (int i = t; i < 64 * 48; i += 256) {
        int sl = i / 48, f = i - sl * 48;
        int axis = f >> 4, j = f & 15;
        float c = coords[(size_t)(b_ * NS + s0 + sl) * 3 + axis];
        float ang = c * powf(10000.0f, -(float)j * (1.0f / 16.0f));
        float sv, cv;
        sincosf(ang, &sv, &cv);
        cst[sl][f] = cv; snt[sl][f] = sv;
    }
    size_t base = (size_t)(bh * NS + s0) * NDH;
    __hip_bfloat16* ptrs[2] = {q + base, k + base};
    #pragma unroll
    for (int pk = 0; pk < 2; ++pk) {
        __hip_bfloat16* p = ptrs[pk];
        __syncthreads();           // pk=0: trig ready; pk=1: tile free
        for (int i = t; i < 64 * NDH; i += 256) tile[i / NDH][i % NDH] = __bfloat162float(p[i]);
        __syncthreads();
        #pragma unroll
        for (int e = 0; e < 24; ++e) {
            int i = t + e * 256;
            int sl = i / NDH, dd = i % NDH;
            int axis = dd >> 5, r = dd & 31, j = r & 15;
            float x1 = tile[sl][(axis << 5) + j];
            float x2 = tile[sl][(axis << 5) + 16 + j];
            float cv = cst[sl][(axis << 4) + j], sv = snt[sl][(axis << 4) + j];
            p[i] = __float2bfloat16((r < 16) ? (x1 * cv - x2 * sv) : (x1 * sv + x2 * cv));
        }
    }
}

// ---------------- MFMA bf16 causal flash attention (bf16 out) ----------------
__global__ __launch_bounds__(256) void attn_mfma(const __hip_bfloat16* __restrict__ q,
                                                 const __hip_bfloat16* __restrict__ k,
                                                 const __hip_bfloat16* __restrict__ v,
                                                 __hip_bfloat16* __restrict__ out) {
    const float scale = 0.1020620726159658f;   // 1/sqrt(96)
    __shared__ __hip_bfloat16 Ks[64][104];
    __shared__ __hip_bfloat16 Vt[96][72];
    __shared__ __hip_bfloat16 Ps[4][32][72];
    int bx = blockIdx.x;
    int bh = bx >> 4, qb = bx & 15;
    int q0 = qb << 7;
    int t = threadIdx.x, w = t >> 6, l = t & 63;
    int lr = l & 15, lg = l >> 4;
    int qw = q0 + (w << 5);
    const __hip_bfloat16* qg = q + (size_t)bh * NS * NDH;
    const __hip_bfloat16* kg = k + (size_t)bh * NS * NDH;
    const __hip_bfloat16* vg = v + (size_t)bh * NS * NDH;

    bf16x8 qa[2][3];
    #pragma unroll
    for (int mt = 0; mt < 2; ++mt)
        #pragma unroll
        for (int ks = 0; ks < 3; ++ks)
            qa[mt][ks] = *(const bf16x8*)&qg[(size_t)(qw + mt*16 + lr) * NDH + ks*32 + lg*8];

    f32x4 acco[2][6];
    #pragma unroll
    for (int mt = 0; mt < 2; ++mt)
        #pragma unroll
        for (int dt = 0; dt < 6; ++dt)
            acco[mt][dt] = (f32x4){0.f, 0.f, 0.f, 0.f};
    float mrow[2][4], lsum[2][4];
    #pragma unroll
    for (int mt = 0; mt < 2; ++mt)
        #pragma unroll
        for (int r = 0; r < 4; ++r) { mrow[mt][r] = -INFINITY; lsum[mt][r] = 0.f; }

    int nch = (q0 + 128) >> 6;
    for (int c = 0; c < nch; ++c) {
        int kv0 = c << 6;
        __syncthreads();
        #pragma unroll
        for (int i = 0; i < 3; ++i) {
            int cc = t + i * 256;
            int row = cc / 12, off = (cc % 12) * 8;
            *(bf16x8*)&Ks[row][off] = *(const bf16x8*)&kg[(size_t)(kv0 + row) * NDH + off];
        }
        {
            int kr = t >> 2, dp = (t & 3) * 24;
            const __hip_bfloat16* vr = &vg[(size_t)(kv0 + kr) * NDH + dp];
            #pragma unroll
            for (int j = 0; j < 24; ++j) Vt[dp + j][kr] = vr[j];
        }
        __syncthreads();
        f32x4 s[2][4];
        #pragma unroll
        for (int mt = 0; mt < 2; ++mt)
            #pragma unroll
            for (int nt = 0; nt < 4; ++nt)
                s[mt][nt] = (f32x4){0.f, 0.f, 0.f, 0.f};
        #pragma unroll
        for (int ks = 0; ks < 3; ++ks) {
            #pragma unroll
            for (int nt = 0; nt < 4; ++nt) {
                bf16x8 kb_ = *(const bf16x8*)&Ks[nt*16 + lr][ks*32 + lg*8];
                #pragma unroll
                for (int mt = 0; mt < 2; ++mt)
                    s[mt][nt] = __builtin_amdgcn_mfma_f32_16x16x32_bf16(qa[mt][ks], kb_, s[mt][nt], 0, 0, 0);
            }
        }
        #pragma unroll
        for (int mt = 0; mt < 2; ++mt) {
            float al[4];
            #pragma unroll
            for (int r = 0; r < 4; ++r) {
                int qrow = qw + mt*16 + lg*4 + r;
                float mx = -INFINITY;
                #pragma unroll
                for (int nt = 0; nt < 4; ++nt) {
                    int col = kv0 + nt*16 + lr;
                    float sc = (col <= qrow) ? s[mt][nt][r] * scale : -INFINITY;
                    s[mt][nt][r] = sc;
                    mx = fmaxf(mx, sc);
                }
                #pragma unroll
                for (int o = 1; o < 16; o <<= 1) mx = fmaxf(mx, __shfl_xor(mx, o));
                float mn = fmaxf(mrow[mt][r], mx);
                al[r] = __expf(mrow[mt][r] - mn);
                mrow[mt][r] = mn;
                float rs = 0.f;
                #pragma unroll
                for (int nt = 0; nt < 4; ++nt) {
                    float p = __expf(s[mt][nt][r] - mn);
                    s[mt][nt][r] = p;
                    rs += p;
                }
                #pragma unroll
                for (int o = 1; o < 16; o <<= 1) rs += __shfl_xor(rs, o);
                lsum[mt][r] = lsum[mt][r] * al[r] + rs;
                #pragma unroll
                for (int nt = 0; nt < 4; ++nt)
                    Ps[w][mt*16 + lg*4 + r][nt*16 + lr] = __float2bfloat16(s[mt][nt][r]);
            }
            #pragma unroll
            for (int dt = 0; dt < 6; ++dt)
                #pragma unroll
                for (int r = 0; r < 4; ++r)
                    acco[mt][dt][r] *= al[r];
        }
        #pragma unroll
        for (int ks = 0; ks < 2; ++ks) {
            bf16x8 pa[2];
            #pragma unroll
            for (int mt = 0; mt < 2; ++mt)
                pa[mt] = *(const bf16x8*)&Ps[w][mt*16 + lr][ks*32 + lg*8];
            #pragma unroll
            for (int dt = 0; dt < 6; ++dt) {
                bf16x8 vb_ = *(const bf16x8*)&Vt[dt*16 + lr][ks*32 + lg*8];
                #pragma unroll
                for (int mt = 0; mt < 2; ++mt)
                    acco[mt][dt] = __builtin_amdgcn_mfma_f32_16x16x32_bf16(pa[mt], vb_, acco[mt][dt], 0, 0, 0);
            }
        }
    }
    int b_ = bh >> 3, hh = bh & 7;
    #pragma unroll
    for (int mt = 0; mt < 2; ++mt) {
        float inv[4];
        #pragma unroll
        for (int r = 0; r < 4; ++r) inv[r] = 1.0f / lsum[mt][r];
        #pragma unroll
        for (int dt = 0; dt < 6; ++dt)
            #pragma unroll
            for (int r = 0; r < 4; ++r) {
                int row = qw + mt*16 + lg*4 + r;
                out[((size_t)(b_ * NS + row)) * ND + hh * NDH + dt*16 + lr] =
                    __float2bfloat16(acco[mt][dt][r] * inv[r]);
            }
    }
}

extern "C" void kernel_launch(void* const* d_in, const int* in_sizes, int n_in,
                              void* d_out, int out_size, void* d_ws, size_t ws_size,
                              hipStream_t stream) {
    const float* src    = (const float*)d_in[0];
    const float* coords = (const float*)d_in[1];
    const float* n1g  = (const float*)d_in[3];
    const float* n1b  = (const float*)d_in[4];
    const float* qkvw = (const float*)d_in[5];
    const float* qkvb = (const float*)d_in[6];
    const float* projw= (const float*)d_in[7];
    const float* projb= (const float*)d_in[8];
    const float* n2g  = (const float*)d_in[9];
    const float* n2b  = (const float*)d_in[10];
    const float* fc1w = (const float*)d_in[11];
    const float* fc1b = (const float*)d_in[12];
    const float* fc2w = (const float*)d_in[13];
    const float* fc2b = (const float*)d_in[14];
    float* out = (float*)d_out;
    float* ws  = (float*)d_ws;

    const size_t N1 = (size_t)NROWS * ND;          // 6291456
    float* x = ws;                                  // [N1] f32 residual stream
    size_t o = N1;
    __hip_bfloat16* qkvwT = (__hip_bfloat16*)(ws + o); o += (768u*2304u)/2;   // +884736
    __hip_bfloat16* projwT= (__hip_bfloat16*)(ws + o); o += (768u*768u)/2;    // +294912
    __hip_bfloat16* fc1wT = (__hip_bfloat16*)(ws + o); o += (768u*3072u)/2;   // +1179648
    __hip_bfloat16* fc2wT = (__hip_bfloat16*)(ws + o); o += (3072u*768u)/2;   // +1179648
    __hip_bfloat16* xnb = (__hip_bfloat16*)(ws + o);   // N1 bf16 (LN1 out; later LN2 out)
    size_t o2 = o + N1 / 2;
    __hip_bfloat16* qbf = (__hip_bfloat16*)(ws + o2);
    __hip_bfloat16* kbf = (__hip_bfloat16*)(ws + o2 + N1 / 2);
    __hip_bfloat16* vbf = (__hip_bfloat16*)(ws + o2 + N1);
    __hip_bfloat16* ao  = (__hip_bfloat16*)(ws + o2 + 3 * N1 / 2);
    __hip_bfloat16* hbuf = qbf;                        // 4*N1 bf16, aliases q/k/v/ao (dead then)

    // 0) weight transpose+convert (every launch; ~10 us total)
    wtrans_kernel<<<dim3((768/32)*(2304/32)), 256, 0, stream>>>(qkvw, qkvwT, 768, 2304);
    wtrans_kernel<<<dim3((768/32)*(768/32)),  256, 0, stream>>>(projw, projwT, 768, 768);
    wtrans_kernel<<<dim3((768/32)*(3072/32)), 256, 0, stream>>>(fc1w, fc1wT, 768, 3072);
    wtrans_kernel<<<dim3((3072/32)*(768/32)), 256, 0, stream>>>(fc2w, fc2wT, 3072, 768);
    // 1) LN1 -> bf16
    ln_bf16_kernel<<<NROWS, 256, 0, stream>>>(src, n1g, n1b, xnb);
    // 2) QKV GEMM + bias, scatter bf16 q/k/v [bh][s][dh]
    gemm_mfma<0><<<dim3(2304/128, NROWS/128), 256, 0, stream>>>(
        xnb, qkvwT, qkvb, NROWS, 2304, ND, nullptr, nullptr, nullptr, qbf, kbf, vbf);
    // 3) RoPE in place on q,k
    rope_bf16_kernel<<<NB * NH * (NS / 64), 256, 0, stream>>>(coords, qbf, kbf);
    // 4) MFMA flash attention -> ao bf16 [B,S,768]
    attn_mfma<<<NB * NH * (NS / 128), 256, 0, stream>>>(qbf, kbf, vbf, ao);
    // 5) proj GEMM + bias + residual(src) -> x f32
    gemm_mfma<1><<<dim3(ND/128, NROWS/128), 256, 0, stream>>>(
        ao, projwT, projb, NROWS, ND, ND, x, src, nullptr, nullptr, nullptr, nullptr);
    // 6) LN2 -> bf16
    ln_bf16_kernel<<<NROWS, 256, 0, stream>>>(x, n2g, n2b, xnb);
    // 7) FC1 GEMM + bias + exact GELU -> bf16
    gemm_mfma<2><<<dim3(NHID/128, NROWS/128), 256, 0, stream>>>(
        xnb, fc1wT, fc1b, NROWS, NHID, ND, nullptr, nullptr, hbuf, nullptr, nullptr, nullptr);
    // 8) FC2 GEMM + bias + residual(x) -> out f32
    gemm_mfma<1><<<dim3(ND/128, NROWS/128), 256, 0, stream>>>(
        hbuf, fc2wT, fc2b, NROWS, ND, NHID, out, x, nullptr, nullptr, nullptr, nullptr);
}

// Round 8
// 472.670 us; speedup vs baseline: 9.2773x; 1.1564x over previous
//
#include <hip/hip_runtime.h>
#include <hip/hip_bf16.h>
#include <math.h>

#define NB 4
#define NS 2048
#define ND 768
#define NH 8
#define NDH 96
#define NHID 3072
#define NROWS (NB*NS)

typedef __attribute__((ext_vector_type(8))) short bf16x8;
typedef __attribute__((ext_vector_type(4))) float f32x4;

// async global->LDS, 16B per lane. LDS dest must be wave-uniform base (HW adds lane*16).
#define GLOAD16(gp, lp)                                                          \
    __builtin_amdgcn_global_load_lds(                                            \
        (__attribute__((address_space(1))) void*)(unsigned long long)(gp),       \
        (__attribute__((address_space(3))) void*)(unsigned long long)(lp), 16, 0, 0)

// ---------------- block-wide sum over 256 threads ----------------
static __device__ __forceinline__ float block_sum256(float v) {
    __shared__ float red[4];
    #pragma unroll
    for (int o = 32; o > 0; o >>= 1) v += __shfl_down(v, o);
    int w = threadIdx.x >> 6;
    __syncthreads();
    if ((threadIdx.x & 63) == 0) red[w] = v;
    __syncthreads();
    return red[0] + red[1] + red[2] + red[3];
}

// ---------------- LayerNorm: f32 in -> bf16 out ----------------
__global__ __launch_bounds__(256) void ln_bf16_kernel(const float* __restrict__ in,
                                                      const float* __restrict__ g,
                                                      const float* __restrict__ bta,
                                                      __hip_bfloat16* __restrict__ out) {
    int row = blockIdx.x;
    const float* x = in + (size_t)row * ND;
    int t = threadIdx.x;
    float v0 = x[t], v1 = x[t + 256], v2 = x[t + 512];
    float mu = block_sum256(v0 + v1 + v2) * (1.0f / ND);
    float d0 = v0 - mu, d1 = v1 - mu, d2 = v2 - mu;
    float var = block_sum256(d0*d0 + d1*d1 + d2*d2) * (1.0f / ND);
    float rs = rsqrtf(var + 1e-6f);
    __hip_bfloat16* o = out + (size_t)row * ND;
    o[t]       = __float2bfloat16(d0 * rs * g[t]       + bta[t]);
    o[t + 256] = __float2bfloat16(d1 * rs * g[t + 256] + bta[t + 256]);
    o[t + 512] = __float2bfloat16(d2 * rs * g[t + 512] + bta[t + 512]);
}

// ---------------- weight transpose+convert: w[K][N] f32 -> wT[N][K] bf16 ----------------
__global__ __launch_bounds__(256) void wtrans_kernel(const float* __restrict__ w,
                                                     __hip_bfloat16* __restrict__ wT,
                                                     int K, int N) {
    __shared__ float tile[32][33];
    int nb = N >> 5;
    int k0 = (blockIdx.x / nb) << 5, n0 = (blockIdx.x % nb) << 5;
    int t = threadIdx.x;
    int rr = t >> 5, cc = t & 31;
    #pragma unroll
    for (int j = 0; j < 4; ++j)
        tile[rr + j*8][cc] = w[(size_t)(k0 + rr + j*8) * N + n0 + cc];
    __syncthreads();
    #pragma unroll
    for (int j = 0; j < 4; ++j)
        wT[(size_t)(n0 + rr + j*8) * K + k0 + cc] = __float2bfloat16(tile[cc][rr + j*8]);
}

// ---------------- bf16 MFMA GEMM: C[M][N] = A[M][K] * BT[N][K]^T ----------------
// 128x128 tile, BK=64, 256 thr (4 waves 2x2), global_load_lds w/ XOR-swizzled source.
// EPI: 0 = +bias, scatter bf16 q/k/v [bh][s][dh]; 1 = +bias+res -> f32; 2 = +bias+GELU -> bf16
template<int EPI>
__global__ __launch_bounds__(256) void gemm_mfma(
        const __hip_bfloat16* __restrict__ A, const __hip_bfloat16* __restrict__ BT,
        const float* __restrict__ bias, int M, int N, int K,
        float* __restrict__ Cf, const float* __restrict__ res,
        __hip_bfloat16* __restrict__ Cb,
        __hip_bfloat16* __restrict__ qo, __hip_bfloat16* __restrict__ ko,
        __hip_bfloat16* __restrict__ vo) {
    __shared__ __attribute__((aligned(16))) __hip_bfloat16 As[128][64];
    __shared__ __attribute__((aligned(16))) __hip_bfloat16 Bs[128][64];
    int bx = blockIdx.x, by = blockIdx.y;
    int t = threadIdx.x, w = t >> 6, l = t & 63;
    int lr = l & 15, lg = l >> 4;
    int wr = w >> 1, wc = w & 1;

    int off  = w * 1024 + l * 16;
    int srow = off >> 7;
    int scol = off & 127;
    int scolS = scol ^ ((srow & 7) << 4);
    const char* ap = (const char*)(A  + (size_t)(by * 128 + srow) * K) + scolS;
    const char* bp = (const char*)(BT + (size_t)(bx * 128 + srow) * K) + scolS;
    size_t rstep = (size_t)32 * K * 2;
    char* asl = ((char*)As) + w * 1024;
    char* bsl = ((char*)Bs) + w * 1024;

    f32x4 acc[4][4];
    #pragma unroll
    for (int i = 0; i < 4; ++i)
        #pragma unroll
        for (int j = 0; j < 4; ++j) acc[i][j] = (f32x4){0.f, 0.f, 0.f, 0.f};

    int mask = (lr & 7) << 4;
    const char* asb = (const char*)As;
    const char* bsb = (const char*)Bs;

    for (int k0 = 0; k0 < K; k0 += 64) {
        __syncthreads();
        #pragma unroll
        for (int i = 0; i < 4; ++i) {
            GLOAD16(ap + i * rstep, asl + i * 4096);
            GLOAD16(bp + i * rstep, bsl + i * 4096);
        }
        ap += 128; bp += 128;
        __syncthreads();
        #pragma unroll
        for (int ks = 0; ks < 2; ++ks) {
            bf16x8 a[4], b[4];
            #pragma unroll
            for (int x = 0; x < 4; ++x) {
                int ra = (wr << 6) + x*16 + lr;
                int rb = (wc << 6) + x*16 + lr;
                int cb = ((ks * 64 + lg * 16) ^ mask);
                a[x] = *(const bf16x8*)(asb + ra * 128 + cb);
                b[x] = *(const bf16x8*)(bsb + rb * 128 + cb);
            }
            #pragma unroll
            for (int mt = 0; mt < 4; ++mt)
                #pragma unroll
                for (int nt = 0; nt < 4; ++nt)
                    acc[mt][nt] = __builtin_amdgcn_mfma_f32_16x16x32_bf16(a[mt], b[nt], acc[mt][nt], 0, 0, 0);
        }
    }

    int rbase = by * 128 + (wr << 6) + lg * 4;
    int cbase = bx * 128 + (wc << 6) + lr;
    #pragma unroll
    for (int nt = 0; nt < 4; ++nt) {
        int gc = cbase + nt * 16;
        float bv = bias[gc];
        #pragma unroll
        for (int mt = 0; mt < 4; ++mt) {
            #pragma unroll
            for (int rr = 0; rr < 4; ++rr) {
                int gr = rbase + mt * 16 + rr;
                float val = acc[mt][nt][rr] + bv;
                if (EPI == 0) {
                    int which = gc / ND;
                    int ccc = gc - which * ND;
                    int hh = ccc / NDH, dd = ccc - hh * NDH;
                    int b_ = gr >> 11, s_ = gr & (NS - 1);
                    __hip_bfloat16* dst = (which == 0) ? qo : (which == 1) ? ko : vo;
                    dst[(size_t)((b_ * NH + hh) * NS + s_) * NDH + dd] = __float2bfloat16(val);
                } else if (EPI == 1) {
                    Cf[(size_t)gr * N + gc] = res[(size_t)gr * N + gc] + val;
                } else {
                    Cb[(size_t)gr * N + gc] =
                        __float2bfloat16(0.5f * val * (1.0f + erff(val * 0.70710678118f)));
                }
            }
        }
    }
}

// ---------------- 3D RoPE: rotate q,k bf16 in place ----------------
__global__ __launch_bounds__(256) void rope_bf16_kernel(const float* __restrict__ coords,
                                                        __hip_bfloat16* __restrict__ q,
                                                        __hip_bfloat16* __restrict__ k) {
    __shared__ float tile[64][97];
    __shared__ float cst[64][49];
    __shared__ float snt[64][49];
    int nblk = NS / 64;
    int bh = blockIdx.x / nblk;
    int s0 = (blockIdx.x % nblk) * 64;
    int b_ = bh / NH;
    int t = threadIdx.x;
    for (int i = t; i < 64 * 48; i += 256) {
        int sl = i / 48, f = i - sl * 48;
        int axis = f >> 4, j = f & 15;
        float c = coords[(size_t)(b_ * NS + s0 + sl) * 3 + axis];
        float ang = c * powf(10000.0f, -(float)j * (1.0f / 16.0f));
        float sv, cv;
        sincosf(ang, &sv, &cv);
        cst[sl][f] = cv; snt[sl][f] = sv;
    }
    size_t base = (size_t)(bh * NS + s0) * NDH;
    __hip_bfloat16* ptrs[2] = {q + base, k + base};
    #pragma unroll
    for (int pk = 0; pk < 2; ++pk) {
        __hip_bfloat16* p = ptrs[pk];
        __syncthreads();
        for (int i = t; i < 64 * NDH; i += 256) tile[i / NDH][i % NDH] = __bfloat162float(p[i]);
        __syncthreads();
        #pragma unroll
        for (int e = 0; e < 24; ++e) {
            int i = t + e * 256;
            int sl = i / NDH, dd = i % NDH;
            int axis = dd >> 5, r = dd & 31, j = r & 15;
            float x1 = tile[sl][(axis << 5) + j];
            float x2 = tile[sl][(axis << 5) + 16 + j];
            float cv = cst[sl][(axis << 4) + j], sv = snt[sl][(axis << 4) + j];
            p[i] = __float2bfloat16((r < 16) ? (x1 * cv - x2 * sv) : (x1 * sv + x2 * cv));
        }
    }
}

// ---------------- MFMA bf16 causal flash attention, LPT-balanced ----------------
// 1024 blocks: bh = bid&31, q-tile = 31-(bid>>5) (longest first). 64 q-rows/block,
// 4 waves x 16 rows. KV chunk = 64, reg-prefetched. V staged transposed with
// wave-uniform-row writes (2-way, free). LDS tiles declared as short: raw bit
// copies only (short->__hip_bfloat16 assignment would NUMERICALLY convert - r6 bug).
__global__ __launch_bounds__(256) void attn_mfma(const __hip_bfloat16* __restrict__ q,
                                                 const __hip_bfloat16* __restrict__ k,
                                                 const __hip_bfloat16* __restrict__ v,
                                                 __hip_bfloat16* __restrict__ out) {
    const float scale = 0.1020620726159658f;   // 1/sqrt(96)
    __shared__ short Ks[64][104];              // K chunk row-major, padded (2-way)
    __shared__ short Vt[96][72];               // V chunk transposed [d][kv] (2-way)
    __shared__ short Ps[4][16][72];            // per-wave P tile
    int bid = blockIdx.x;
    int bh = bid & 31;
    int tq = 31 - (bid >> 5);                  // LPT: longest blocks dispatch first
    int q0 = tq << 6;
    int t = threadIdx.x, w = t >> 6, l = t & 63;
    int lr = l & 15, lg = l >> 4;
    int qw = q0 + (w << 4);                    // wave's 16 q-rows
    const __hip_bfloat16* qg = q + (size_t)bh * NS * NDH;
    const __hip_bfloat16* kg = k + (size_t)bh * NS * NDH;
    const __hip_bfloat16* vg = v + (size_t)bh * NS * NDH;

    // Q fragments: A[16q][32d] per ks: lane -> row lr, k = lg*8..+7
    bf16x8 qa[3];
    #pragma unroll
    for (int ks = 0; ks < 3; ++ks)
        qa[ks] = *(const bf16x8*)&qg[(size_t)(qw + lr) * NDH + ks*32 + lg*8];

    f32x4 acco[6];
    #pragma unroll
    for (int dt = 0; dt < 6; ++dt) acco[dt] = (f32x4){0.f, 0.f, 0.f, 0.f};
    float mrow[4], lsum[4];
    #pragma unroll
    for (int r = 0; r < 4; ++r) { mrow[r] = -INFINITY; lsum[r] = 0.f; }

    // staging coords: K: 768 16B-pieces over 256 thr x3; V: lane=k, wave-uniform d-row
    int krow[3], koff[3];
    #pragma unroll
    for (int i = 0; i < 3; ++i) {
        int cc = t + i * 256;
        krow[i] = cc / 12; koff[i] = (cc % 12) * 8;
    }
    bf16x8 kreg[3], vreg[3];
    #pragma unroll
    for (int i = 0; i < 3; ++i) {
        kreg[i] = *(const bf16x8*)&kg[(size_t)krow[i] * NDH + koff[i]];
        vreg[i] = *(const bf16x8*)&vg[(size_t)l * NDH + (w + 4*i) * 8];
    }

    int nch = tq + 1;
    for (int c = 0; c < nch; ++c) {
        int kv0 = c << 6;
        __syncthreads();                       // prior compute done with LDS
        #pragma unroll
        for (int i = 0; i < 3; ++i)
            *(bf16x8*)&Ks[krow[i]][koff[i]] = kreg[i];
        #pragma unroll
        for (int i = 0; i < 3; ++i) {
            int d0 = (w + 4*i) * 8;
            #pragma unroll
            for (int j = 0; j < 8; ++j) Vt[d0 + j][l] = vreg[i][j];  // short->short bit copy
        }
        __syncthreads();
        if (c + 1 < nch) {                     // prefetch next chunk under compute
            int kv1 = (c + 1) << 6;
            #pragma unroll
            for (int i = 0; i < 3; ++i) {
                kreg[i] = *(const bf16x8*)&kg[(size_t)(kv1 + krow[i]) * NDH + koff[i]];
                vreg[i] = *(const bf16x8*)&vg[(size_t)(kv1 + l) * NDH + (w + 4*i) * 8];
            }
        }
        // QK^T: S[16q][64kv]
        f32x4 s[4];
        #pragma unroll
        for (int nt = 0; nt < 4; ++nt) s[nt] = (f32x4){0.f, 0.f, 0.f, 0.f};
        #pragma unroll
        for (int ks = 0; ks < 3; ++ks) {
            #pragma unroll
            for (int nt = 0; nt < 4; ++nt) {
                bf16x8 kb_ = *(const bf16x8*)&Ks[nt*16 + lr][ks*32 + lg*8];
                s[nt] = __builtin_amdgcn_mfma_f32_16x16x32_bf16(qa[ks], kb_, s[nt], 0, 0, 0);
            }
        }
        // online softmax; C layout: row = lg*4+r, col = nt*16+lr
        float al[4];
        #pragma unroll
        for (int r = 0; r < 4; ++r) {
            int qrow = qw + lg*4 + r;
            float mx = -INFINITY;
            #pragma unroll
            for (int nt = 0; nt < 4; ++nt) {
                int col = kv0 + nt*16 + lr;
                float sc = (col <= qrow) ? s[nt][r] * scale : -INFINITY;
                s[nt][r] = sc;
                mx = fmaxf(mx, sc);
            }
            #pragma unroll
            for (int o = 1; o < 16; o <<= 1) mx = fmaxf(mx, __shfl_xor(mx, o));
            float mn = fmaxf(mrow[r], mx);
            al[r] = __expf(mrow[r] - mn);       // first chunk: exp(-inf)=0
            mrow[r] = mn;
            float rs = 0.f;
            #pragma unroll
            for (int nt = 0; nt < 4; ++nt) {
                float p = __expf(s[nt][r] - mn);
                s[nt][r] = p;
                rs += p;
            }
            #pragma unroll
            for (int o = 1; o < 16; o <<= 1) rs += __shfl_xor(rs, o);
            lsum[r] = lsum[r] * al[r] + rs;
            #pragma unroll
            for (int nt = 0; nt < 4; ++nt) {
                __hip_bfloat16 pb = __float2bfloat16(s[nt][r]);
                Ps[w][lg*4 + r][nt*16 + lr] = *(const short*)&pb;
            }
        }
        #pragma unroll
        for (int dt = 0; dt < 6; ++dt)
            #pragma unroll
            for (int r = 0; r < 4; ++r)
                acco[dt][r] *= al[r];
        // PV: O[16q][96d] += P[16x64] x V[64x96]
        #pragma unroll
        for (int ks = 0; ks < 2; ++ks) {
            bf16x8 pa = *(const bf16x8*)&Ps[w][lr][ks*32 + lg*8];
            #pragma unroll
            for (int dt = 0; dt < 6; ++dt) {
                bf16x8 vb_ = *(const bf16x8*)&Vt[dt*16 + lr][ks*32 + lg*8];
                acco[dt] = __builtin_amdgcn_mfma_f32_16x16x32_bf16(pa, vb_, acco[dt], 0, 0, 0);
            }
        }
    }
    // epilogue: divide by l, write bf16 to [B][S][768]
    int b_ = bh >> 3, hh = bh & 7;
    float inv[4];
    #pragma unroll
    for (int r = 0; r < 4; ++r) inv[r] = 1.0f / lsum[r];
    #pragma unroll
    for (int dt = 0; dt < 6; ++dt)
        #pragma unroll
        for (int r = 0; r < 4; ++r) {
            int row = qw + lg*4 + r;
            out[((size_t)(b_ * NS + row)) * ND + hh * NDH + dt*16 + lr] =
                __float2bfloat16(acco[dt][r] * inv[r]);
        }
}

extern "C" void kernel_launch(void* const* d_in, const int* in_sizes, int n_in,
                              void* d_out, int out_size, void* d_ws, size_t ws_size,
                              hipStream_t stream) {
    const float* src    = (const float*)d_in[0];
    const float* coords = (const float*)d_in[1];
    const float* n1g  = (const float*)d_in[3];
    const float* n1b  = (const float*)d_in[4];
    const float* qkvw = (const float*)d_in[5];
    const float* qkvb = (const float*)d_in[6];
    const float* projw= (const float*)d_in[7];
    const float* projb= (const float*)d_in[8];
    const float* n2g  = (const float*)d_in[9];
    const float* n2b  = (const float*)d_in[10];
    const float* fc1w = (const float*)d_in[11];
    const float* fc1b = (const float*)d_in[12];
    const float* fc2w = (const float*)d_in[13];
    const float* fc2b = (const float*)d_in[14];
    float* out = (float*)d_out;
    float* ws  = (float*)d_ws;

    const size_t N1 = (size_t)NROWS * ND;          // 6291456
    float* x = ws;                                  // [N1] f32 residual stream
    size_t o = N1;
    __hip_bfloat16* qkvwT = (__hip_bfloat16*)(ws + o); o += (768u*2304u)/2;
    __hip_bfloat16* projwT= (__hip_bfloat16*)(ws + o); o += (768u*768u)/2;
    __hip_bfloat16* fc1wT = (__hip_bfloat16*)(ws + o); o += (768u*3072u)/2;
    __hip_bfloat16* fc2wT = (__hip_bfloat16*)(ws + o); o += (3072u*768u)/2;
    __hip_bfloat16* xnb = (__hip_bfloat16*)(ws + o);   // N1 bf16 (LN1 out; later LN2 out)
    size_t o2 = o + N1 / 2;
    __hip_bfloat16* qbf = (__hip_bfloat16*)(ws + o2);
    __hip_bfloat16* kbf = (__hip_bfloat16*)(ws + o2 + N1 / 2);
    __hip_bfloat16* vbf = (__hip_bfloat16*)(ws + o2 + N1);
    __hip_bfloat16* ao  = (__hip_bfloat16*)(ws + o2 + 3 * N1 / 2);
    __hip_bfloat16* hbuf = qbf;                        // 4*N1 bf16, aliases q/k/v/ao

    // 0) weight transpose+convert
    wtrans_kernel<<<dim3((768/32)*(2304/32)), 256, 0, stream>>>(qkvw, qkvwT, 768, 2304);
    wtrans_kernel<<<dim3((768/32)*(768/32)),  256, 0, stream>>>(projw, projwT, 768, 768);
    wtrans_kernel<<<dim3((768/32)*(3072/32)), 256, 0, stream>>>(fc1w, fc1wT, 768, 3072);
    wtrans_kernel<<<dim3((3072/32)*(768/32)), 256, 0, stream>>>(fc2w, fc2wT, 3072, 768);
    // 1) LN1 -> bf16
    ln_bf16_kernel<<<NROWS, 256, 0, stream>>>(src, n1g, n1b, xnb);
    // 2) QKV GEMM + bias, scatter bf16 q/k/v [bh][s][dh]
    gemm_mfma<0><<<dim3(2304/128, NROWS/128), 256, 0, stream>>>(
        xnb, qkvwT, qkvb, NROWS, 2304, ND, nullptr, nullptr, nullptr, qbf, kbf, vbf);
    // 3) RoPE in place on q,k
    rope_bf16_kernel<<<NB * NH * (NS / 64), 256, 0, stream>>>(coords, qbf, kbf);
    // 4) MFMA flash attention -> ao bf16 [B,S,768]
    attn_mfma<<<1024, 256, 0, stream>>>(qbf, kbf, vbf, ao);
    // 5) proj GEMM + bias + residual(src) -> x f32
    gemm_mfma<1><<<dim3(ND/128, NROWS/128), 256, 0, stream>>>(
        ao, projwT, projb, NROWS, ND, ND, x, src, nullptr, nullptr, nullptr, nullptr);
    // 6) LN2 -> bf16
    ln_bf16_kernel<<<NROWS, 256, 0, stream>>>(x, n2g, n2b, xnb);
    // 7) FC1 GEMM + bias + exact GELU -> bf16
    gemm_mfma<2><<<dim3(NHID/128, NROWS/128), 256, 0, stream>>>(
        xnb, fc1wT, fc1b, NROWS, NHID, ND, nullptr, nullptr, hbuf, nullptr, nullptr, nullptr);
    // 8) FC2 GEMM + bias + residual(x) -> out f32
    gemm_mfma<1><<<dim3(ND/128, NROWS/128), 256, 0, stream>>>(
        hbuf, fc2wT, fc2b, NROWS, ND, NHID, out, x, nullptr, nullptr, nullptr, nullptr);
}

// Round 9
// 465.216 us; speedup vs baseline: 9.4259x; 1.0160x over previous
//
#include <hip/hip_runtime.h>
#include <hip/hip_bf16.h>
#include <math.h>

#define NB 4
#define NS 2048
#define ND 768
#define NH 8
#define NDH 96
#define NHID 3072
#define NROWS (NB*NS)

typedef __attribute__((ext_vector_type(8))) short bf16x8;
typedef __attribute__((ext_vector_type(4))) float f32x4;

// async global->LDS, 16B per lane. LDS dest must be wave-uniform base (HW adds lane*16).
#define GLOAD16(gp, lp)                                                          \
    __builtin_amdgcn_global_load_lds(                                            \
        (__attribute__((address_space(1))) void*)(unsigned long long)(gp),       \
        (__attribute__((address_space(3))) void*)(unsigned long long)(lp), 16, 0, 0)

// ---------------- block-wide sum over 256 threads ----------------
static __device__ __forceinline__ float block_sum256(float v) {
    __shared__ float red[4];
    #pragma unroll
    for (int o = 32; o > 0; o >>= 1) v += __shfl_down(v, o);
    int w = threadIdx.x >> 6;
    __syncthreads();
    if ((threadIdx.x & 63) == 0) red[w] = v;
    __syncthreads();
    return red[0] + red[1] + red[2] + red[3];
}

// ---------------- LayerNorm: f32 in -> bf16 out ----------------
__global__ __launch_bounds__(256) void ln_bf16_kernel(const float* __restrict__ in,
                                                      const float* __restrict__ g,
                                                      const float* __restrict__ bta,
                                                      __hip_bfloat16* __restrict__ out) {
    int row = blockIdx.x;
    const float* x = in + (size_t)row * ND;
    int t = threadIdx.x;
    float v0 = x[t], v1 = x[t + 256], v2 = x[t + 512];
    float mu = block_sum256(v0 + v1 + v2) * (1.0f / ND);
    float d0 = v0 - mu, d1 = v1 - mu, d2 = v2 - mu;
    float var = block_sum256(d0*d0 + d1*d1 + d2*d2) * (1.0f / ND);
    float rs = rsqrtf(var + 1e-6f);
    __hip_bfloat16* o = out + (size_t)row * ND;
    o[t]       = __float2bfloat16(d0 * rs * g[t]       + bta[t]);
    o[t + 256] = __float2bfloat16(d1 * rs * g[t + 256] + bta[t + 256]);
    o[t + 512] = __float2bfloat16(d2 * rs * g[t + 512] + bta[t + 512]);
}

// ---------------- weight transpose+convert: w[K][N] f32 -> wT[N][K] bf16 ----------------
__global__ __launch_bounds__(256) void wtrans_kernel(const float* __restrict__ w,
                                                     __hip_bfloat16* __restrict__ wT,
                                                     int K, int N) {
    __shared__ float tile[32][33];
    int nb = N >> 5;
    int k0 = (blockIdx.x / nb) << 5, n0 = (blockIdx.x % nb) << 5;
    int t = threadIdx.x;
    int rr = t >> 5, cc = t & 31;
    #pragma unroll
    for (int j = 0; j < 4; ++j)
        tile[rr + j*8][cc] = w[(size_t)(k0 + rr + j*8) * N + n0 + cc];
    __syncthreads();
    #pragma unroll
    for (int j = 0; j < 4; ++j)
        wT[(size_t)(n0 + rr + j*8) * K + k0 + cc] = __float2bfloat16(tile[cc][rr + j*8]);
}

// ---------------- bf16 MFMA GEMM: C[M][N] = A[M][K] * BT[N][K]^T ----------------
// 128x128 tile, BK=64, 256 thr (4 waves 2x2), global_load_lds w/ XOR-swizzled source.
// EPI: 0 = +bias, scatter bf16 q/k/v [bh][s][dh]; 1 = +bias+res -> f32; 2 = +bias+GELU -> bf16
template<int EPI>
__global__ __launch_bounds__(256) void gemm_mfma(
        const __hip_bfloat16* __restrict__ A, const __hip_bfloat16* __restrict__ BT,
        const float* __restrict__ bias, int M, int N, int K,
        float* __restrict__ Cf, const float* __restrict__ res,
        __hip_bfloat16* __restrict__ Cb,
        __hip_bfloat16* __restrict__ qo, __hip_bfloat16* __restrict__ ko,
        __hip_bfloat16* __restrict__ vo) {
    __shared__ __attribute__((aligned(16))) __hip_bfloat16 As[128][64];
    __shared__ __attribute__((aligned(16))) __hip_bfloat16 Bs[128][64];
    int bx = blockIdx.x, by = blockIdx.y;
    int t = threadIdx.x, w = t >> 6, l = t & 63;
    int lr = l & 15, lg = l >> 4;
    int wr = w >> 1, wc = w & 1;

    int off  = w * 1024 + l * 16;
    int srow = off >> 7;
    int scol = off & 127;
    int scolS = scol ^ ((srow & 7) << 4);
    const char* ap = (const char*)(A  + (size_t)(by * 128 + srow) * K) + scolS;
    const char* bp = (const char*)(BT + (size_t)(bx * 128 + srow) * K) + scolS;
    size_t rstep = (size_t)32 * K * 2;
    char* asl = ((char*)As) + w * 1024;
    char* bsl = ((char*)Bs) + w * 1024;

    f32x4 acc[4][4];
    #pragma unroll
    for (int i = 0; i < 4; ++i)
        #pragma unroll
        for (int j = 0; j < 4; ++j) acc[i][j] = (f32x4){0.f, 0.f, 0.f, 0.f};

    int mask = (lr & 7) << 4;
    const char* asb = (const char*)As;
    const char* bsb = (const char*)Bs;

    for (int k0 = 0; k0 < K; k0 += 64) {
        __syncthreads();
        #pragma unroll
        for (int i = 0; i < 4; ++i) {
            GLOAD16(ap + i * rstep, asl + i * 4096);
            GLOAD16(bp + i * rstep, bsl + i * 4096);
        }
        ap += 128; bp += 128;
        __syncthreads();
        #pragma unroll
        for (int ks = 0; ks < 2; ++ks) {
            bf16x8 a[4], b[4];
            #pragma unroll
            for (int x = 0; x < 4; ++x) {
                int ra = (wr << 6) + x*16 + lr;
                int rb = (wc << 6) + x*16 + lr;
                int cb = ((ks * 64 + lg * 16) ^ mask);
                a[x] = *(const bf16x8*)(asb + ra * 128 + cb);
                b[x] = *(const bf16x8*)(bsb + rb * 128 + cb);
            }
            #pragma unroll
            for (int mt = 0; mt < 4; ++mt)
                #pragma unroll
                for (int nt = 0; nt < 4; ++nt)
                    acc[mt][nt] = __builtin_amdgcn_mfma_f32_16x16x32_bf16(a[mt], b[nt], acc[mt][nt], 0, 0, 0);
        }
    }

    int rbase = by * 128 + (wr << 6) + lg * 4;
    int cbase = bx * 128 + (wc << 6) + lr;
    #pragma unroll
    for (int nt = 0; nt < 4; ++nt) {
        int gc = cbase + nt * 16;
        float bv = bias[gc];
        #pragma unroll
        for (int mt = 0; mt < 4; ++mt) {
            #pragma unroll
            for (int rr = 0; rr < 4; ++rr) {
                int gr = rbase + mt * 16 + rr;
                float val = acc[mt][nt][rr] + bv;
                if (EPI == 0) {
                    int which = gc / ND;
                    int ccc = gc - which * ND;
                    int hh = ccc / NDH, dd = ccc - hh * NDH;
                    int b_ = gr >> 11, s_ = gr & (NS - 1);
                    __hip_bfloat16* dst = (which == 0) ? qo : (which == 1) ? ko : vo;
                    dst[(size_t)((b_ * NH + hh) * NS + s_) * NDH + dd] = __float2bfloat16(val);
                } else if (EPI == 1) {
                    Cf[(size_t)gr * N + gc] = res[(size_t)gr * N + gc] + val;
                } else {
                    Cb[(size_t)gr * N + gc] =
                        __float2bfloat16(0.5f * val * (1.0f + erff(val * 0.70710678118f)));
                }
            }
        }
    }
}

// ---------------- 3D RoPE: rotate q,k bf16 in place ----------------
__global__ __launch_bounds__(256) void rope_bf16_kernel(const float* __restrict__ coords,
                                                        __hip_bfloat16* __restrict__ q,
                                                        __hip_bfloat16* __restrict__ k) {
    __shared__ float tile[64][97];
    __shared__ float cst[64][49];
    __shared__ float snt[64][49];
    int nblk = NS / 64;
    int bh = blockIdx.x / nblk;
    int s0 = (blockIdx.x % nblk) * 64;
    int b_ = bh / NH;
    int t = threadIdx.x;
    for (int i = t; i < 64 * 48; i += 256) {
        int sl = i / 48, f = i - sl * 48;
        int axis = f >> 4, j = f & 15;
        float c = coords[(size_t)(b_ * NS + s0 + sl) * 3 + axis];
        float ang = c * powf(10000.0f, -(float)j * (1.0f / 16.0f));
        float sv, cv;
        sincosf(ang, &sv, &cv);
        cst[sl][f] = cv; snt[sl][f] = sv;
    }
    size_t base = (size_t)(bh * NS + s0) * NDH;
    __hip_bfloat16* ptrs[2] = {q + base, k + base};
    #pragma unroll
    for (int pk = 0; pk < 2; ++pk) {
        __hip_bfloat16* p = ptrs[pk];
        __syncthreads();
        for (int i = t; i < 64 * NDH; i += 256) tile[i / NDH][i % NDH] = __bfloat162float(p[i]);
        __syncthreads();
        #pragma unroll
        for (int e = 0; e < 24; ++e) {
            int i = t + e * 256;
            int sl = i / NDH, dd = i % NDH;
            int axis = dd >> 5, r = dd & 31, j = r & 15;
            float x1 = tile[sl][(axis << 5) + j];
            float x2 = tile[sl][(axis << 5) + 16 + j];
            float cv = cst[sl][(axis << 4) + j], sv = snt[sl][(axis << 4) + j];
            p[i] = __float2bfloat16((r < 16) ? (x1 * cv - x2 * sv) : (x1 * sv + x2 * cv));
        }
    }
}

// ---------------- MFMA bf16 causal flash attention ----------------
// 512 blocks: bh = bid&31, pair p = bid>>5; block processes q-tiles {p, 31-p}
// sequentially -> uniform 33 chunks/block (perfect balance, no tail).
// LDS XOR-swizzled (short idx ^= (row&7)<<3, both sides) -> conflict-free b128.
// LDS declared short: bit copies only (short->bf16 assignment converts - r6 bug).
__global__ __launch_bounds__(256) void attn_mfma(const __hip_bfloat16* __restrict__ q,
                                                 const __hip_bfloat16* __restrict__ k,
                                                 const __hip_bfloat16* __restrict__ v,
                                                 __hip_bfloat16* __restrict__ out) {
    const float scale = 0.1020620726159658f;   // 1/sqrt(96)
    __shared__ short Ks[64][128];              // 256B rows (192B used), swizzled
    __shared__ short Vt[96][64];               // [d][kv], 128B rows, swizzled
    __shared__ short Ps[4][16][64];            // per-wave P, 128B rows, swizzled
    int bid = blockIdx.x;
    int bh = bid & 31;
    int pr = bid >> 5;                         // 0..15
    int t = threadIdx.x, w = t >> 6, l = t & 63;
    int lr = l & 15, lg = l >> 4;
    const __hip_bfloat16* qg = q + (size_t)bh * NS * NDH;
    const __hip_bfloat16* kg = k + (size_t)bh * NS * NDH;
    const __hip_bfloat16* vg = v + (size_t)bh * NS * NDH;
    int b_ = bh >> 3, hh = bh & 7;

    // K staging coords: 768 16B-pieces over 256 thr x3
    int krow[3], kslot[3];
    #pragma unroll
    for (int i = 0; i < 3; ++i) {
        int cc = t + i * 256;
        krow[i] = cc / 12; kslot[i] = cc % 12;
    }
    int rdsw = (lr & 7) << 3;                  // read-side swizzle (short idx)

    #pragma unroll
    for (int half = 0; half < 2; ++half) {
        int tq = half ? (31 - pr) : pr;
        int q0 = tq << 6;
        int qw = q0 + (w << 4);                // wave's 16 q-rows

        bf16x8 qa[3];
        #pragma unroll
        for (int ks = 0; ks < 3; ++ks)
            qa[ks] = *(const bf16x8*)&qg[(size_t)(qw + lr) * NDH + ks*32 + lg*8];

        f32x4 acco[6];
        #pragma unroll
        for (int dt = 0; dt < 6; ++dt) acco[dt] = (f32x4){0.f, 0.f, 0.f, 0.f};
        float mrow[4], lsum[4];
        #pragma unroll
        for (int r = 0; r < 4; ++r) { mrow[r] = -INFINITY; lsum[r] = 0.f; }

        // prefetch chunk 0
        bf16x8 kreg[3], vreg[3];
        #pragma unroll
        for (int i = 0; i < 3; ++i) {
            kreg[i] = *(const bf16x8*)&kg[(size_t)krow[i] * NDH + kslot[i]*8];
            vreg[i] = *(const bf16x8*)&vg[(size_t)l * NDH + (w + 4*i) * 8];
        }

        for (int c = 0; c <= tq; ++c) {
            int kv0 = c << 6;
            __syncthreads();                   // prior compute done with LDS
            #pragma unroll
            for (int i = 0; i < 3; ++i)
                *(bf16x8*)&Ks[krow[i]][(kslot[i]*8) ^ ((krow[i] & 7) << 3)] = kreg[i];
            #pragma unroll
            for (int i = 0; i < 3; ++i) {
                int d0 = (w + 4*i) * 8;        // d0&7 == 0 -> row&7 == j
                #pragma unroll
                for (int j = 0; j < 8; ++j) Vt[d0 + j][l ^ (j << 3)] = vreg[i][j];
            }
            __syncthreads();
            if (c < tq) {                      // prefetch next chunk under compute
                int kv1 = (c + 1) << 6;
                #pragma unroll
                for (int i = 0; i < 3; ++i) {
                    kreg[i] = *(const bf16x8*)&kg[(size_t)(kv1 + krow[i]) * NDH + kslot[i]*8];
                    vreg[i] = *(const bf16x8*)&vg[(size_t)(kv1 + l) * NDH + (w + 4*i) * 8];
                }
            }
            // QK^T: S[16q][64kv]
            f32x4 s[4];
            #pragma unroll
            for (int nt = 0; nt < 4; ++nt) s[nt] = (f32x4){0.f, 0.f, 0.f, 0.f};
            #pragma unroll
            for (int ks = 0; ks < 3; ++ks) {
                #pragma unroll
                for (int nt = 0; nt < 4; ++nt) {
                    bf16x8 kb_ = *(const bf16x8*)&Ks[nt*16 + lr][(ks*32 + lg*8) ^ rdsw];
                    s[nt] = __builtin_amdgcn_mfma_f32_16x16x32_bf16(qa[ks], kb_, s[nt], 0, 0, 0);
                }
            }
            // scale (+ mask only on the diagonal chunk)
            if (c == tq) {
                #pragma unroll
                for (int r = 0; r < 4; ++r) {
                    int qrow = qw + lg*4 + r;
                    #pragma unroll
                    for (int nt = 0; nt < 4; ++nt) {
                        int col = kv0 + nt*16 + lr;
                        s[nt][r] = (col <= qrow) ? s[nt][r] * scale : -INFINITY;
                    }
                }
            } else {
                #pragma unroll
                for (int nt = 0; nt < 4; ++nt)
                    #pragma unroll
                    for (int r = 0; r < 4; ++r) s[nt][r] *= scale;
            }
            // online softmax; C layout: row = lg*4+r, col = nt*16+lr
            float al[4];
            #pragma unroll
            for (int r = 0; r < 4; ++r) {
                float mx = fmaxf(fmaxf(s[0][r], s[1][r]), fmaxf(s[2][r], s[3][r]));
                #pragma unroll
                for (int o = 1; o < 16; o <<= 1) mx = fmaxf(mx, __shfl_xor(mx, o));
                float mn = fmaxf(mrow[r], mx);
                al[r] = __expf(mrow[r] - mn);   // first chunk: exp(-inf)=0
                mrow[r] = mn;
                float rs = 0.f;
                #pragma unroll
                for (int nt = 0; nt < 4; ++nt) {
                    float p = __expf(s[nt][r] - mn);
                    s[nt][r] = p;
                    rs += p;
                }
                #pragma unroll
                for (int o = 1; o < 16; o <<= 1) rs += __shfl_xor(rs, o);
                lsum[r] = lsum[r] * al[r] + rs;
                int prow = lg*4 + r;
                #pragma unroll
                for (int nt = 0; nt < 4; ++nt) {
                    __hip_bfloat16 pb = __float2bfloat16(s[nt][r]);
                    Ps[w][prow][(nt*16 + lr) ^ ((prow & 7) << 3)] = *(const short*)&pb;
                }
            }
            #pragma unroll
            for (int dt = 0; dt < 6; ++dt)
                #pragma unroll
                for (int r = 0; r < 4; ++r)
                    acco[dt][r] *= al[r];
            // PV: O[16q][96d] += P[16x64] x V[64x96]
            #pragma unroll
            for (int ks = 0; ks < 2; ++ks) {
                bf16x8 pa = *(const bf16x8*)&Ps[w][lr][(ks*32 + lg*8) ^ rdsw];
                #pragma unroll
                for (int dt = 0; dt < 6; ++dt) {
                    bf16x8 vb_ = *(const bf16x8*)&Vt[dt*16 + lr][(ks*32 + lg*8) ^ rdsw];
                    acco[dt] = __builtin_amdgcn_mfma_f32_16x16x32_bf16(pa, vb_, acco[dt], 0, 0, 0);
                }
            }
        }
        // epilogue: divide by l, write bf16 to [B][S][768]
        float inv[4];
        #pragma unroll
        for (int r = 0; r < 4; ++r) inv[r] = 1.0f / lsum[r];
        #pragma unroll
        for (int dt = 0; dt < 6; ++dt)
            #pragma unroll
            for (int r = 0; r < 4; ++r) {
                int row = qw + lg*4 + r;
                out[((size_t)(b_ * NS + row)) * ND + hh * NDH + dt*16 + lr] =
                    __float2bfloat16(acco[dt][r] * inv[r]);
            }
    }
}

extern "C" void kernel_launch(void* const* d_in, const int* in_sizes, int n_in,
                              void* d_out, int out_size, void* d_ws, size_t ws_size,
                              hipStream_t stream) {
    const float* src    = (const float*)d_in[0];
    const float* coords = (const float*)d_in[1];
    const float* n1g  = (const float*)d_in[3];
    const float* n1b  = (const float*)d_in[4];
    const float* qkvw = (const float*)d_in[5];
    const float* qkvb = (const float*)d_in[6];
    const float* projw= (const float*)d_in[7];
    const float* projb= (const float*)d_in[8];
    const float* n2g  = (const float*)d_in[9];
    const float* n2b  = (const float*)d_in[10];
    const float* fc1w = (const float*)d_in[11];
    const float* fc1b = (const float*)d_in[12];
    const float* fc2w = (const float*)d_in[13];
    const float* fc2b = (const float*)d_in[14];
    float* out = (float*)d_out;
    float* ws  = (float*)d_ws;

    const size_t N1 = (size_t)NROWS * ND;          // 6291456
    float* x = ws;                                  // [N1] f32 residual stream
    size_t o = N1;
    __hip_bfloat16* qkvwT = (__hip_bfloat16*)(ws + o); o += (768u*2304u)/2;
    __hip_bfloat16* projwT= (__hip_bfloat16*)(ws + o); o += (768u*768u)/2;
    __hip_bfloat16* fc1wT = (__hip_bfloat16*)(ws + o); o += (768u*3072u)/2;
    __hip_bfloat16* fc2wT = (__hip_bfloat16*)(ws + o); o += (3072u*768u)/2;
    __hip_bfloat16* xnb = (__hip_bfloat16*)(ws + o);   // N1 bf16 (LN1 out; later LN2 out)
    size_t o2 = o + N1 / 2;
    __hip_bfloat16* qbf = (__hip_bfloat16*)(ws + o2);
    __hip_bfloat16* kbf = (__hip_bfloat16*)(ws + o2 + N1 / 2);
    __hip_bfloat16* vbf = (__hip_bfloat16*)(ws + o2 + N1);
    __hip_bfloat16* ao  = (__hip_bfloat16*)(ws + o2 + 3 * N1 / 2);
    __hip_bfloat16* hbuf = qbf;                        // 4*N1 bf16, aliases q/k/v/ao

    // 0) weight transpose+convert
    wtrans_kernel<<<dim3((768/32)*(2304/32)), 256, 0, stream>>>(qkvw, qkvwT, 768, 2304);
    wtrans_kernel<<<dim3((768/32)*(768/32)),  256, 0, stream>>>(projw, projwT, 768, 768);
    wtrans_kernel<<<dim3((768/32)*(3072/32)), 256, 0, stream>>>(fc1w, fc1wT, 768, 3072);
    wtrans_kernel<<<dim3((3072/32)*(768/32)), 256, 0, stream>>>(fc2w, fc2wT, 3072, 768);
    // 1) LN1 -> bf16
    ln_bf16_kernel<<<NROWS, 256, 0, stream>>>(src, n1g, n1b, xnb);
    // 2) QKV GEMM + bias, scatter bf16 q/k/v [bh][s][dh]
    gemm_mfma<0><<<dim3(2304/128, NROWS/128), 256, 0, stream>>>(
        xnb, qkvwT, qkvb, NROWS, 2304, ND, nullptr, nullptr, nullptr, qbf, kbf, vbf);
    // 3) RoPE in place on q,k
    rope_bf16_kernel<<<NB * NH * (NS / 64), 256, 0, stream>>>(coords, qbf, kbf);
    // 4) MFMA flash attention -> ao bf16 [B,S,768]
    attn_mfma<<<512, 256, 0, stream>>>(qbf, kbf, vbf, ao);
    // 5) proj GEMM + bias + residual(src) -> x f32
    gemm_mfma<1><<<dim3(ND/128, NROWS/128), 256, 0, stream>>>(
        ao, projwT, projb, NROWS, ND, ND, x, src, nullptr, nullptr, nullptr, nullptr);
    // 6) LN2 -> bf16
    ln_bf16_kernel<<<NROWS, 256, 0, stream>>>(x, n2g, n2b, xnb);
    // 7) FC1 GEMM + bias + exact GELU -> bf16
    gemm_mfma<2><<<dim3(NHID/128, NROWS/128), 256, 0, stream>>>(
        xnb, fc1wT, fc1b, NROWS, NHID, ND, nullptr, nullptr, hbuf, nullptr, nullptr, nullptr);
    // 8) FC2 GEMM + bias + residual(x) -> out f32
    gemm_mfma<1><<<dim3(ND/128, NROWS/128), 256, 0, stream>>>(
        hbuf, fc2wT, fc2b, NROWS, ND, NHID, out, x, nullptr, nullptr, nullptr, nullptr);
}